// Round 1
// baseline (3197.965 us; speedup 1.0000x reference)
//
#include <hip/hip_runtime.h>
#include <math.h>

#define B_ 16
#define N_ 4096
#define D_ 64
#define H_ 128
#define K_ 32
#define NS_ 1024
#define R2_ 0.04f
#define CAP_ 1024

// ---------------- FPS: one block per cloud, bit-exact vs numpy ----------------
__global__ __launch_bounds__(1024) void fps_kernel(
    const float* __restrict__ pos, int* __restrict__ idx_i,
    float* __restrict__ idx_f, float* __restrict__ pos_s)
{
    __shared__ float lpos[N_ * 3];
    __shared__ float red_v[2][16];
    __shared__ int   red_i[2][16];
    const int b = blockIdx.x;
    const int t = threadIdx.x;
    const float* posb = pos + (size_t)b * N_ * 3;
    for (int i = t; i < N_ * 3; i += 1024) lpos[i] = posb[i];
    __syncthreads();

    float px[4], py[4], pz[4], dist[4];
#pragma unroll
    for (int j = 0; j < 4; ++j) {
        int p = t + j * 1024;
        px[j] = lpos[3 * p + 0];
        py[j] = lpos[3 * p + 1];
        pz[j] = lpos[3 * p + 2];
        dist[j] = 1e10f;
    }
    int cur = 0;
    const int lane = t & 63;
    const int wv = t >> 6;
    for (int ns = 0; ns < NS_; ++ns) {
        if (t == 0) {
            idx_i[b * NS_ + ns] = cur;
            idx_f[b * NS_ + ns] = (float)cur;
            pos_s[(b * NS_ + ns) * 3 + 0] = lpos[3 * cur + 0];
            pos_s[(b * NS_ + ns) * 3 + 1] = lpos[3 * cur + 1];
            pos_s[(b * NS_ + ns) * 3 + 2] = lpos[3 * cur + 2];
        }
        float cx = lpos[3 * cur + 0], cy = lpos[3 * cur + 1], cz = lpos[3 * cur + 2];
        float bv = -1.f; int bi = 0x7fffffff;
#pragma unroll
        for (int j = 0; j < 4; ++j) {
            float dx = __fsub_rn(px[j], cx);
            float dy = __fsub_rn(py[j], cy);
            float dz = __fsub_rn(pz[j], cz);
            float d2 = __fadd_rn(__fadd_rn(__fmul_rn(dx, dx), __fmul_rn(dy, dy)), __fmul_rn(dz, dz));
            float dn = fminf(dist[j], d2);
            dist[j] = dn;
            int p = t + j * 1024;
            if (dn > bv || (dn == bv && p < bi)) { bv = dn; bi = p; }
        }
#pragma unroll
        for (int off = 32; off; off >>= 1) {
            float ov = __shfl_xor(bv, off);
            int   oi = __shfl_xor(bi, off);
            if (ov > bv || (ov == bv && oi < bi)) { bv = ov; bi = oi; }
        }
        if (lane == 0) { red_v[ns & 1][wv] = bv; red_i[ns & 1][wv] = bi; }
        __syncthreads();
        float v = red_v[ns & 1][0]; int ii = red_i[ns & 1][0];
#pragma unroll
        for (int w = 1; w < 16; ++w) {
            float wvv = red_v[ns & 1][w]; int wii = red_i[ns & 1][w];
            if (wvv > v || (wvv == v && wii < ii)) { v = wvv; ii = wii; }
        }
        cur = ii;
    }
}

// ---------------- radius-KNN: one wave per sample ----------------
__global__ __launch_bounds__(256) void nbr_kernel(
    const float* __restrict__ pos, const float* __restrict__ pos_s,
    int* __restrict__ nbr, float* __restrict__ cntv)
{
    __shared__ float cd2[4][CAP_];
    __shared__ int   ci[4][CAP_];
    const int w = threadIdx.x >> 6;
    const int lane = threadIdx.x & 63;
    const int s = blockIdx.x * 4 + w;
    const int b = s >> 10;
    const float cx = pos_s[s * 3 + 0], cy = pos_s[s * 3 + 1], cz = pos_s[s * 3 + 2];
    const float* posb = pos + (size_t)b * N_ * 3;
    int m = 0;
    for (int base = 0; base < N_; base += 64) {
        int p = base + lane;
        float dx = __fsub_rn(posb[3 * p + 0], cx);
        float dy = __fsub_rn(posb[3 * p + 1], cy);
        float dz = __fsub_rn(posb[3 * p + 2], cz);
        float d2 = __fadd_rn(__fadd_rn(__fmul_rn(dx, dx), __fmul_rn(dy, dy)), __fmul_rn(dz, dz));
        bool in = (d2 <= R2_);
        unsigned long long msk = __ballot(in);
        int before = __popcll(msk & ((1ull << lane) - 1ull));
        int slot = m + before;
        if (in && slot < CAP_) { cd2[w][slot] = d2; ci[w][slot] = p; }
        m += __popcll(msk);
    }
    if (m > CAP_) m = CAP_;
    __asm__ volatile("s_waitcnt lgkmcnt(0)" ::: "memory");
    int kcnt = m < K_ ? m : K_;
    unsigned chosen = 0;  // bit r: slot (lane + 64*r) consumed
    for (int k = 0; k < kcnt; ++k) {
        float bv = 3.0e38f; int bi = 0x7fffffff; int bslot = -1;
        for (int r = 0; r * 64 + lane < m; ++r) {
            if (chosen & (1u << r)) continue;
            int q = r * 64 + lane;
            float v = cd2[w][q]; int ii = ci[w][q];
            if (v < bv || (v == bv && ii < bi)) { bv = v; bi = ii; bslot = q; }
        }
#pragma unroll
        for (int off = 32; off; off >>= 1) {
            float ov = __shfl_xor(bv, off);
            int   oi = __shfl_xor(bi, off);
            int   os = __shfl_xor(bslot, off);
            if (ov < bv || (ov == bv && oi < bi)) { bv = ov; bi = oi; bslot = os; }
        }
        if (lane == (bslot & 63)) chosen |= 1u << (bslot >> 6);
        if (lane == 0) nbr[s * K_ + k] = bi;
    }
    if (lane == 0) {
        for (int k = kcnt; k < K_; ++k) nbr[s * K_ + k] = -1;
        cntv[s] = (float)kcnt;
    }
}

// ---------------- message MLP + aggregation: one block (128 thr) per sample ----------------
__global__ __launch_bounds__(128) void msg_kernel(
    const float* __restrict__ x, const float* __restrict__ pos,
    const float* __restrict__ W1, const float* __restrict__ b1,
    const float* __restrict__ W2, const float* __restrict__ b2,
    const float* __restrict__ pos_s, const int* __restrict__ nbr,
    const float* __restrict__ cntv, float* __restrict__ aggr_x,
    float* __restrict__ out_pos)
{
    __shared__ float feat[K_][68];    // 64 x_j + dist + 3 zero pad (16B-aligned rows)
    __shared__ float embs[K_][132];
    __shared__ float sdiff[K_][4];
    __shared__ float spw[K_][4];
    __shared__ float svalid[K_];
    __shared__ float sW2t[3][128];
    const int s = blockIdx.x;
    const int b = s >> 10;
    const int t = threadIdx.x;
    {
        float v0 = W2[t * 3 + 0], v1 = W2[t * 3 + 1], v2 = W2[t * 3 + 2];
        sW2t[0][t] = v0; sW2t[1][t] = v1; sW2t[2][t] = v2;
    }
    const float cx = pos_s[s * 3 + 0], cy = pos_s[s * 3 + 1], cz = pos_s[s * 3 + 2];
    const int k = t >> 2, part = t & 3;
    const int n = nbr[s * K_ + k];
    if (part == 0) {
        if (n >= 0) {
            const float* pj = pos + ((size_t)b * N_ + n) * 3;
            float dx = __fsub_rn(pj[0], cx);
            float dy = __fsub_rn(pj[1], cy);
            float dz = __fsub_rn(pj[2], cz);
            float d2 = __fadd_rn(__fadd_rn(__fmul_rn(dx, dx), __fmul_rn(dy, dy)), __fmul_rn(dz, dz));
            float dd = d2 > 0.f ? sqrtf(d2) : 0.f;
            feat[k][64] = dd; feat[k][65] = 0.f; feat[k][66] = 0.f; feat[k][67] = 0.f;
            sdiff[k][0] = dx; sdiff[k][1] = dy; sdiff[k][2] = dz;
            svalid[k] = 1.f;
        } else {
            feat[k][64] = feat[k][65] = feat[k][66] = feat[k][67] = 0.f;
            sdiff[k][0] = sdiff[k][1] = sdiff[k][2] = 0.f;
            svalid[k] = 0.f;
        }
    }
    {
        float4* fr = (float4*)&feat[k][0];
        if (n >= 0) {
            const float4* xr = (const float4*)(x + ((size_t)b * N_ + n) * D_);
#pragma unroll
            for (int q = 0; q < 4; ++q) fr[part * 4 + q] = xr[part * 4 + q];
        } else {
            float4 z = make_float4(0.f, 0.f, 0.f, 0.f);
#pragma unroll
            for (int q = 0; q < 4; ++q) fr[part * 4 + q] = z;
        }
    }
    // W1 column for h = t lives in registers
    float w1c[68];
#pragma unroll
    for (int j = 0; j < 65; ++j) w1c[j] = W1[j * H_ + t];
    w1c[65] = w1c[66] = w1c[67] = 0.f;
    __syncthreads();
    float acc[K_];
#pragma unroll
    for (int kk = 0; kk < K_; ++kk) acc[kk] = 0.f;
#pragma unroll
    for (int j4 = 0; j4 < 17; ++j4) {
#pragma unroll
        for (int kk = 0; kk < K_; ++kk) {
            float4 f = *(const float4*)&feat[kk][j4 * 4];
            float a = acc[kk];
            a = fmaf(f.x, w1c[j4 * 4 + 0], a);
            a = fmaf(f.y, w1c[j4 * 4 + 1], a);
            a = fmaf(f.z, w1c[j4 * 4 + 2], a);
            a = fmaf(f.w, w1c[j4 * 4 + 3], a);
            acc[kk] = a;
        }
    }
    const float bt = b1[t];
    float ag = 0.f;
#pragma unroll
    for (int kk = 0; kk < K_; ++kk) {
        float e = acc[kk] + bt;
        e = e > 0.f ? e : 0.f;
        embs[kk][t] = e;
        ag = fmaf(svalid[kk], e, ag);
    }
    aggr_x[(size_t)s * H_ + t] = ag;
    __syncthreads();
    if (t < 96) {
        const int kk = t / 3, c = t - 3 * (t / 3);
        float d = 0.f;
        const float4* er = (const float4*)&embs[kk][0];
        const float4* wr = (const float4*)&sW2t[c][0];
#pragma unroll
        for (int q = 0; q < 32; ++q) {
            float4 a = er[q], wq = wr[q];
            d = fmaf(a.x, wq.x, d); d = fmaf(a.y, wq.y, d);
            d = fmaf(a.z, wq.z, d); d = fmaf(a.w, wq.w, d);
        }
        d += b2[c];
        spw[kk][c] = d * sdiff[kk][c] * svalid[kk];   // masked pmsg component
    }
    __syncthreads();
    if (t < 3) {
        float ssum = 0.f;
        for (int kk = 0; kk < K_; ++kk) ssum += spw[kk][t];
        float cnt = cntv[s]; if (cnt < 1.f) cnt = 1.f;
        out_pos[s * 3 + t] = pos_s[s * 3 + t] + ssum / cnt;
    }
}

// ---------------- update GEMM: relu([x_d, aggr_x] @ W3 + b3) ----------------
__global__ __launch_bounds__(128) void out_kernel(
    const float* __restrict__ x, const float* __restrict__ W3,
    const float* __restrict__ b3, const int* __restrict__ idx_i,
    const float* __restrict__ aggr_x, float* __restrict__ out_x)
{
    __shared__ float rows[32][208];
    const int t = threadIdx.x;
    const int s0 = blockIdx.x * 32;
    const int sl = t >> 2, part = t & 3;
    const int s = s0 + sl;
    const int b = s >> 10;
    const int id = idx_i[s];
    {
        const float4* xr = (const float4*)(x + ((size_t)b * N_ + id) * D_);
        float4* rr = (float4*)&rows[sl][0];
#pragma unroll
        for (int q = 0; q < 4; ++q) rr[part * 4 + q] = xr[part * 4 + q];
        const float4* ar = (const float4*)(aggr_x + (size_t)s * H_);
        float4* rr2 = (float4*)&rows[sl][64];
#pragma unroll
        for (int q = 0; q < 8; ++q) rr2[part * 8 + q] = ar[part * 8 + q];
    }
    __syncthreads();
    float acc[32];
#pragma unroll
    for (int i = 0; i < 32; ++i) acc[i] = 0.f;
    for (int j4 = 0; j4 < 48; ++j4) {
        float w0 = W3[(j4 * 4 + 0) * H_ + t];
        float w1 = W3[(j4 * 4 + 1) * H_ + t];
        float w2 = W3[(j4 * 4 + 2) * H_ + t];
        float w3 = W3[(j4 * 4 + 3) * H_ + t];
#pragma unroll
        for (int i = 0; i < 32; ++i) {
            const float4 f = *(const float4*)&rows[i][j4 * 4];
            float a = acc[i];
            a = fmaf(f.x, w0, a); a = fmaf(f.y, w1, a);
            a = fmaf(f.z, w2, a); a = fmaf(f.w, w3, a);
            acc[i] = a;
        }
    }
    const float bb = b3[t];
#pragma unroll
    for (int i = 0; i < 32; ++i) {
        float v = acc[i] + bb;
        v = v > 0.f ? v : 0.f;
        out_x[(size_t)(s0 + i) * H_ + t] = v;
    }
}

extern "C" void kernel_launch(void* const* d_in, const int* in_sizes, int n_in,
                              void* d_out, int out_size, void* d_ws, size_t ws_size,
                              hipStream_t stream) {
    const float* x   = (const float*)d_in[0];
    const float* pos = (const float*)d_in[1];
    const float* W1  = (const float*)d_in[2];
    const float* b1  = (const float*)d_in[3];
    const float* W2  = (const float*)d_in[4];
    const float* b2  = (const float*)d_in[5];
    const float* W3  = (const float*)d_in[6];
    const float* b3  = (const float*)d_in[7];

    float* out_x   = (float*)d_out;                       // [16,1024,128]
    float* out_pos = (float*)d_out + 2097152;             // [16,1024,3]
    float* idx_f   = (float*)d_out + 2146304;             // [16,1024] as float

    char* ws = (char*)d_ws;
    int*   idx_i  = (int*)ws;                  // 16384 ints
    float* pos_s  = (float*)(ws + 65536);      // 49152 floats
    int*   nbr    = (int*)(ws + 262144);       // 524288 ints
    float* cntv   = (float*)(ws + 2359296);    // 16384 floats
    float* aggr_x = (float*)(ws + 2424832);    // 2097152 floats (ends ~10.3 MB)

    fps_kernel<<<B_, 1024, 0, stream>>>(pos, idx_i, idx_f, pos_s);
    nbr_kernel<<<(B_ * NS_) / 4, 256, 0, stream>>>(pos, pos_s, nbr, cntv);
    msg_kernel<<<B_ * NS_, 128, 0, stream>>>(x, pos, W1, b1, W2, b2,
                                             pos_s, nbr, cntv, aggr_x, out_pos);
    out_kernel<<<(B_ * NS_) / 32, 128, 0, stream>>>(x, W3, b3, idx_i, aggr_x, out_x);
}

// Round 2
// 2056.858 us; speedup vs baseline: 1.5548x; 1.5548x over previous
//
#include <hip/hip_runtime.h>
#include <math.h>

#define B_ 16
#define N_ 4096
#define D_ 64
#define H_ 128
#define K_ 32
#define NS_ 1024
#define R2_ 0.04f
#define CAP_ 1024

// ---------------- FPS v2: one block (256 thr) per cloud ----------------
// Packed-key argmax: key = (bits(dist)<<32) | (0xFFFFFFFF - idx)  (dist>=0)
// -> u64 max == (max dist, lowest index on tie). Winner lane carries coords
// into a per-wave LDS slot; one barrier per iteration (double-buffered slots).
__global__ __launch_bounds__(256) void fps_kernel(
    const float* __restrict__ pos, int* __restrict__ idx_i,
    float* __restrict__ idx_f, float* __restrict__ pos_s)
{
    __shared__ float4 lpos4[N_];                         // 64 KB, padded xyz
    __shared__ unsigned long long skey[2][4];
    __shared__ float4 scoord[2][4];
    const int b = blockIdx.x;
    const int t = threadIdx.x;
    const int wv = t >> 6;
    const float* posb = pos + (size_t)b * N_ * 3;
    for (int p = t; p < N_; p += 256)
        lpos4[p] = make_float4(posb[3 * p + 0], posb[3 * p + 1], posb[3 * p + 2], 0.f);
    __syncthreads();

    float px[16], py[16], pz[16], dist[16];
#pragma unroll
    for (int j = 0; j < 16; ++j) {
        float4 v = lpos4[t + 256 * j];
        px[j] = v.x; py[j] = v.y; pz[j] = v.z;
        dist[j] = 1e10f;
    }
    unsigned curidx = 0;
    float4 c0 = lpos4[0];
    float ccx = c0.x, ccy = c0.y, ccz = c0.z;

    for (int ns = 0; ns < NS_; ++ns) {
        if (t == 0) {
            idx_i[b * NS_ + ns] = (int)curidx;
            idx_f[b * NS_ + ns] = (float)curidx;
            pos_s[(b * NS_ + ns) * 3 + 0] = ccx;
            pos_s[(b * NS_ + ns) * 3 + 1] = ccy;
            pos_s[(b * NS_ + ns) * 3 + 2] = ccz;
        }
        float bv = -1.f; int bj = 0;
#pragma unroll
        for (int j = 0; j < 16; ++j) {
            float dx = __fsub_rn(px[j], ccx);
            float dy = __fsub_rn(py[j], ccy);
            float dz = __fsub_rn(pz[j], ccz);
            float d2 = __fadd_rn(__fadd_rn(__fmul_rn(dx, dx), __fmul_rn(dy, dy)), __fmul_rn(dz, dz));
            float dn = fminf(dist[j], d2);
            dist[j] = dn;
            bool g = dn > bv;                 // strict > + ascending j => lowest idx on tie
            bv = g ? dn : bv;
            bj = g ? j : bj;
        }
        const unsigned pid = (unsigned)t + ((unsigned)bj << 8);
        const unsigned long long mykey =
            ((unsigned long long)__float_as_uint(bv) << 32) | (unsigned long long)(0xFFFFFFFFu - pid);
        unsigned long long k2 = mykey;
#pragma unroll
        for (int off = 32; off; off >>= 1) {
            unsigned long long o = __shfl_xor(k2, off);
            if (o > k2) k2 = o;
        }
        if (k2 == mykey)                       // unique winner lane per wave
        {
            skey[ns & 1][wv] = mykey;
            scoord[ns & 1][wv] = make_float4(px[bj], py[bj], pz[bj], 0.f);
        }
        __syncthreads();
        unsigned long long ka = skey[ns & 1][0], kb = skey[ns & 1][1];
        unsigned long long kc = skey[ns & 1][2], kd = skey[ns & 1][3];
        float4 ca = scoord[ns & 1][0], cb = scoord[ns & 1][1];
        float4 cc = scoord[ns & 1][2], cd = scoord[ns & 1][3];
        if (kb > ka) { ka = kb; ca = cb; }
        if (kd > kc) { kc = kd; cc = cd; }
        if (kc > ka) { ka = kc; ca = cc; }
        curidx = 0xFFFFFFFFu - (unsigned)(ka & 0xFFFFFFFFull);
        ccx = ca.x; ccy = ca.y; ccz = ca.z;
    }
}

// ---------------- radius-KNN: one wave per sample ----------------
__global__ __launch_bounds__(256) void nbr_kernel(
    const float* __restrict__ pos, const float* __restrict__ pos_s,
    int* __restrict__ nbr, float* __restrict__ cntv)
{
    __shared__ float cd2[4][CAP_];
    __shared__ int   ci[4][CAP_];
    const int w = threadIdx.x >> 6;
    const int lane = threadIdx.x & 63;
    const int s = blockIdx.x * 4 + w;
    const int b = s >> 10;
    const float cx = pos_s[s * 3 + 0], cy = pos_s[s * 3 + 1], cz = pos_s[s * 3 + 2];
    const float* posb = pos + (size_t)b * N_ * 3;
    int m = 0;
    for (int base = 0; base < N_; base += 64) {
        int p = base + lane;
        float dx = __fsub_rn(posb[3 * p + 0], cx);
        float dy = __fsub_rn(posb[3 * p + 1], cy);
        float dz = __fsub_rn(posb[3 * p + 2], cz);
        float d2 = __fadd_rn(__fadd_rn(__fmul_rn(dx, dx), __fmul_rn(dy, dy)), __fmul_rn(dz, dz));
        bool in = (d2 <= R2_);
        unsigned long long msk = __ballot(in);
        int before = __popcll(msk & ((1ull << lane) - 1ull));
        int slot = m + before;
        if (in && slot < CAP_) { cd2[w][slot] = d2; ci[w][slot] = p; }
        m += __popcll(msk);
    }
    if (m > CAP_) m = CAP_;
    __asm__ volatile("s_waitcnt lgkmcnt(0)" ::: "memory");
    int kcnt = m < K_ ? m : K_;
    unsigned chosen = 0;  // bit r: slot (lane + 64*r) consumed
    for (int k = 0; k < kcnt; ++k) {
        float bv = 3.0e38f; int bi = 0x7fffffff; int bslot = -1;
        for (int r = 0; r * 64 + lane < m; ++r) {
            if (chosen & (1u << r)) continue;
            int q = r * 64 + lane;
            float v = cd2[w][q]; int ii = ci[w][q];
            if (v < bv || (v == bv && ii < bi)) { bv = v; bi = ii; bslot = q; }
        }
#pragma unroll
        for (int off = 32; off; off >>= 1) {
            float ov = __shfl_xor(bv, off);
            int   oi = __shfl_xor(bi, off);
            int   os = __shfl_xor(bslot, off);
            if (ov < bv || (ov == bv && oi < bi)) { bv = ov; bi = oi; bslot = os; }
        }
        if (lane == (bslot & 63)) chosen |= 1u << (bslot >> 6);
        if (lane == 0) nbr[s * K_ + k] = bi;
    }
    if (lane == 0) {
        for (int k = kcnt; k < K_; ++k) nbr[s * K_ + k] = -1;
        cntv[s] = (float)kcnt;
    }
}

// ---------------- message MLP + aggregation: one block (128 thr) per sample ----------------
__global__ __launch_bounds__(128) void msg_kernel(
    const float* __restrict__ x, const float* __restrict__ pos,
    const float* __restrict__ W1, const float* __restrict__ b1,
    const float* __restrict__ W2, const float* __restrict__ b2,
    const float* __restrict__ pos_s, const int* __restrict__ nbr,
    const float* __restrict__ cntv, float* __restrict__ aggr_x,
    float* __restrict__ out_pos)
{
    __shared__ float feat[K_][68];    // 64 x_j + dist + 3 zero pad (16B-aligned rows)
    __shared__ float embs[K_][132];
    __shared__ float sdiff[K_][4];
    __shared__ float spw[K_][4];
    __shared__ float svalid[K_];
    __shared__ float sW2t[3][128];
    const int s = blockIdx.x;
    const int b = s >> 10;
    const int t = threadIdx.x;
    {
        float v0 = W2[t * 3 + 0], v1 = W2[t * 3 + 1], v2 = W2[t * 3 + 2];
        sW2t[0][t] = v0; sW2t[1][t] = v1; sW2t[2][t] = v2;
    }
    const float cx = pos_s[s * 3 + 0], cy = pos_s[s * 3 + 1], cz = pos_s[s * 3 + 2];
    const int k = t >> 2, part = t & 3;
    const int n = nbr[s * K_ + k];
    if (part == 0) {
        if (n >= 0) {
            const float* pj = pos + ((size_t)b * N_ + n) * 3;
            float dx = __fsub_rn(pj[0], cx);
            float dy = __fsub_rn(pj[1], cy);
            float dz = __fsub_rn(pj[2], cz);
            float d2 = __fadd_rn(__fadd_rn(__fmul_rn(dx, dx), __fmul_rn(dy, dy)), __fmul_rn(dz, dz));
            float dd = d2 > 0.f ? sqrtf(d2) : 0.f;
            feat[k][64] = dd; feat[k][65] = 0.f; feat[k][66] = 0.f; feat[k][67] = 0.f;
            sdiff[k][0] = dx; sdiff[k][1] = dy; sdiff[k][2] = dz;
            svalid[k] = 1.f;
        } else {
            feat[k][64] = feat[k][65] = feat[k][66] = feat[k][67] = 0.f;
            sdiff[k][0] = sdiff[k][1] = sdiff[k][2] = 0.f;
            svalid[k] = 0.f;
        }
    }
    {
        float4* fr = (float4*)&feat[k][0];
        if (n >= 0) {
            const float4* xr = (const float4*)(x + ((size_t)b * N_ + n) * D_);
#pragma unroll
            for (int q = 0; q < 4; ++q) fr[part * 4 + q] = xr[part * 4 + q];
        } else {
            float4 z = make_float4(0.f, 0.f, 0.f, 0.f);
#pragma unroll
            for (int q = 0; q < 4; ++q) fr[part * 4 + q] = z;
        }
    }
    // W1 column for h = t lives in registers
    float w1c[68];
#pragma unroll
    for (int j = 0; j < 65; ++j) w1c[j] = W1[j * H_ + t];
    w1c[65] = w1c[66] = w1c[67] = 0.f;
    __syncthreads();
    float acc[K_];
#pragma unroll
    for (int kk = 0; kk < K_; ++kk) acc[kk] = 0.f;
#pragma unroll
    for (int j4 = 0; j4 < 17; ++j4) {
#pragma unroll
        for (int kk = 0; kk < K_; ++kk) {
            float4 f = *(const float4*)&feat[kk][j4 * 4];
            float a = acc[kk];
            a = fmaf(f.x, w1c[j4 * 4 + 0], a);
            a = fmaf(f.y, w1c[j4 * 4 + 1], a);
            a = fmaf(f.z, w1c[j4 * 4 + 2], a);
            a = fmaf(f.w, w1c[j4 * 4 + 3], a);
            acc[kk] = a;
        }
    }
    const float bt = b1[t];
    float ag = 0.f;
#pragma unroll
    for (int kk = 0; kk < K_; ++kk) {
        float e = acc[kk] + bt;
        e = e > 0.f ? e : 0.f;
        embs[kk][t] = e;
        ag = fmaf(svalid[kk], e, ag);
    }
    aggr_x[(size_t)s * H_ + t] = ag;
    __syncthreads();
    if (t < 96) {
        const int kk = t / 3, c = t - 3 * (t / 3);
        float d = 0.f;
        const float4* er = (const float4*)&embs[kk][0];
        const float4* wr = (const float4*)&sW2t[c][0];
#pragma unroll
        for (int q = 0; q < 32; ++q) {
            float4 a = er[q], wq = wr[q];
            d = fmaf(a.x, wq.x, d); d = fmaf(a.y, wq.y, d);
            d = fmaf(a.z, wq.z, d); d = fmaf(a.w, wq.w, d);
        }
        d += b2[c];
        spw[kk][c] = d * sdiff[kk][c] * svalid[kk];   // masked pmsg component
    }
    __syncthreads();
    if (t < 3) {
        float ssum = 0.f;
        for (int kk = 0; kk < K_; ++kk) ssum += spw[kk][t];
        float cnt = cntv[s]; if (cnt < 1.f) cnt = 1.f;
        out_pos[s * 3 + t] = pos_s[s * 3 + t] + ssum / cnt;
    }
}

// ---------------- update GEMM: relu([x_d, aggr_x] @ W3 + b3) ----------------
__global__ __launch_bounds__(128) void out_kernel(
    const float* __restrict__ x, const float* __restrict__ W3,
    const float* __restrict__ b3, const int* __restrict__ idx_i,
    const float* __restrict__ aggr_x, float* __restrict__ out_x)
{
    __shared__ float rows[32][208];
    const int t = threadIdx.x;
    const int s0 = blockIdx.x * 32;
    const int sl = t >> 2, part = t & 3;
    const int s = s0 + sl;
    const int b = s >> 10;
    const int id = idx_i[s];
    {
        const float4* xr = (const float4*)(x + ((size_t)b * N_ + id) * D_);
        float4* rr = (float4*)&rows[sl][0];
#pragma unroll
        for (int q = 0; q < 4; ++q) rr[part * 4 + q] = xr[part * 4 + q];
        const float4* ar = (const float4*)(aggr_x + (size_t)s * H_);
        float4* rr2 = (float4*)&rows[sl][64];
#pragma unroll
        for (int q = 0; q < 8; ++q) rr2[part * 8 + q] = ar[part * 8 + q];
    }
    __syncthreads();
    float acc[32];
#pragma unroll
    for (int i = 0; i < 32; ++i) acc[i] = 0.f;
    for (int j4 = 0; j4 < 48; ++j4) {
        float w0 = W3[(j4 * 4 + 0) * H_ + t];
        float w1 = W3[(j4 * 4 + 1) * H_ + t];
        float w2 = W3[(j4 * 4 + 2) * H_ + t];
        float w3 = W3[(j4 * 4 + 3) * H_ + t];
#pragma unroll
        for (int i = 0; i < 32; ++i) {
            const float4 f = *(const float4*)&rows[i][j4 * 4];
            float a = acc[i];
            a = fmaf(f.x, w0, a); a = fmaf(f.y, w1, a);
            a = fmaf(f.z, w2, a); a = fmaf(f.w, w3, a);
            acc[i] = a;
        }
    }
    const float bb = b3[t];
#pragma unroll
    for (int i = 0; i < 32; ++i) {
        float v = acc[i] + bb;
        v = v > 0.f ? v : 0.f;
        out_x[(size_t)(s0 + i) * H_ + t] = v;
    }
}

extern "C" void kernel_launch(void* const* d_in, const int* in_sizes, int n_in,
                              void* d_out, int out_size, void* d_ws, size_t ws_size,
                              hipStream_t stream) {
    const float* x   = (const float*)d_in[0];
    const float* pos = (const float*)d_in[1];
    const float* W1  = (const float*)d_in[2];
    const float* b1  = (const float*)d_in[3];
    const float* W2  = (const float*)d_in[4];
    const float* b2  = (const float*)d_in[5];
    const float* W3  = (const float*)d_in[6];
    const float* b3  = (const float*)d_in[7];

    float* out_x   = (float*)d_out;                       // [16,1024,128]
    float* out_pos = (float*)d_out + 2097152;             // [16,1024,3]
    float* idx_f   = (float*)d_out + 2146304;             // [16,1024] as float

    char* ws = (char*)d_ws;
    int*   idx_i  = (int*)ws;                  // 16384 ints
    float* pos_s  = (float*)(ws + 65536);      // 49152 floats
    int*   nbr    = (int*)(ws + 262144);       // 524288 ints
    float* cntv   = (float*)(ws + 2359296);    // 16384 floats
    float* aggr_x = (float*)(ws + 2424832);    // 2097152 floats (ends ~10.3 MB)

    fps_kernel<<<B_, 256, 0, stream>>>(pos, idx_i, idx_f, pos_s);
    nbr_kernel<<<(B_ * NS_) / 4, 256, 0, stream>>>(pos, pos_s, nbr, cntv);
    msg_kernel<<<B_ * NS_, 128, 0, stream>>>(x, pos, W1, b1, W2, b2,
                                             pos_s, nbr, cntv, aggr_x, out_pos);
    out_kernel<<<(B_ * NS_) / 32, 128, 0, stream>>>(x, W3, b3, idx_i, aggr_x, out_x);
}

// Round 3
// 2034.062 us; speedup vs baseline: 1.5722x; 1.0112x over previous
//
#include <hip/hip_runtime.h>
#include <math.h>

#define B_ 16
#define N_ 4096
#define D_ 64
#define H_ 128
#define K_ 32
#define NS_ 1024
#define R2_ 0.04f
#define CAP_ 1024
#define S_MSG 4

// ---------------- FPS v3: one block (256 thr) per cloud ----------------
// Packed-key argmax (u64 max == max dist, lowest index on tie). Winner lane
// carries coords to a per-wave LDS slot. All per-iteration results go to LDS
// (sres); global write-out happens once at the end, so no vmcnt drain sits on
// the per-iteration barrier path.
__global__ __launch_bounds__(256) void fps_kernel(
    const float* __restrict__ pos, int* __restrict__ idx_i,
    float* __restrict__ idx_f, float* __restrict__ pos_s)
{
    __shared__ float4 lpos4[N_];                         // 64 KB
    __shared__ float4 sres[NS_];                         // 16 KB: x,y,z,bits(idx)
    __shared__ unsigned long long skey[2][4];
    __shared__ float4 scoord[2][4];
    const int b = blockIdx.x;
    const int t = threadIdx.x;
    const int wv = t >> 6;
    const float* posb = pos + (size_t)b * N_ * 3;
    for (int p = t; p < N_; p += 256)
        lpos4[p] = make_float4(posb[3 * p + 0], posb[3 * p + 1], posb[3 * p + 2], 0.f);
    __syncthreads();

    float px[16], py[16], pz[16], dist[16];
#pragma unroll
    for (int j = 0; j < 16; ++j) {
        float4 v = lpos4[t + 256 * j];
        px[j] = v.x; py[j] = v.y; pz[j] = v.z;
        dist[j] = 1e10f;
    }
    unsigned curidx = 0;
    float4 c0 = lpos4[0];
    float ccx = c0.x, ccy = c0.y, ccz = c0.z;

    for (int ns = 0; ns < NS_; ++ns) {
        if (t == 0)
            sres[ns] = make_float4(ccx, ccy, ccz, __uint_as_float(curidx));
        float bv = -1.f; int bj = 0;
#pragma unroll
        for (int j = 0; j < 16; ++j) {
            float dx = __fsub_rn(px[j], ccx);
            float dy = __fsub_rn(py[j], ccy);
            float dz = __fsub_rn(pz[j], ccz);
            float d2 = __fadd_rn(__fadd_rn(__fmul_rn(dx, dx), __fmul_rn(dy, dy)), __fmul_rn(dz, dz));
            float dn = fminf(dist[j], d2);
            dist[j] = dn;
            bool g = dn > bv;                 // strict > + ascending j => lowest idx on tie
            bv = g ? dn : bv;
            bj = g ? j : bj;
        }
        const unsigned pid = (unsigned)t + ((unsigned)bj << 8);
        const unsigned long long mykey =
            ((unsigned long long)__float_as_uint(bv) << 32) | (unsigned long long)(0xFFFFFFFFu - pid);
        unsigned long long k2 = mykey;
#pragma unroll
        for (int off = 32; off; off >>= 1) {
            unsigned long long o = __shfl_xor(k2, off);
            if (o > k2) k2 = o;
        }
        if (k2 == mykey) {                     // unique winner lane per wave
            skey[ns & 1][wv] = mykey;
            scoord[ns & 1][wv] = make_float4(px[bj], py[bj], pz[bj], 0.f);
        }
        __syncthreads();
        unsigned long long ka = skey[ns & 1][0], kb = skey[ns & 1][1];
        unsigned long long kc = skey[ns & 1][2], kd = skey[ns & 1][3];
        float4 ca = scoord[ns & 1][0], cb = scoord[ns & 1][1];
        float4 cc = scoord[ns & 1][2], cd = scoord[ns & 1][3];
        if (kb > ka) { ka = kb; ca = cb; }
        if (kd > kc) { kc = kd; cc = cd; }
        if (kc > ka) { ka = kc; ca = cc; }
        curidx = 0xFFFFFFFFu - (unsigned)(ka & 0xFFFFFFFFull);
        ccx = ca.x; ccy = ca.y; ccz = ca.z;
    }
    __syncthreads();
    for (int i = t; i < NS_; i += 256) {
        float4 r = sres[i];
        unsigned id = __float_as_uint(r.w);
        idx_i[b * NS_ + i] = (int)id;
        idx_f[b * NS_ + i] = (float)id;
        pos_s[(b * NS_ + i) * 3 + 0] = r.x;
        pos_s[(b * NS_ + i) * 3 + 1] = r.y;
        pos_s[(b * NS_ + i) * 3 + 2] = r.z;
    }
}

// ---------------- radius-KNN v2: one wave per sample, u64 packed keys ------
__global__ __launch_bounds__(256) void nbr_kernel(
    const float* __restrict__ pos, const float* __restrict__ pos_s,
    int* __restrict__ nbr, float* __restrict__ cntv)
{
    __shared__ unsigned long long ck[4][CAP_];           // 32 KB
    const int w = threadIdx.x >> 6;
    const int lane = threadIdx.x & 63;
    const int s = blockIdx.x * 4 + w;
    const int b = s >> 10;
    const float cx = pos_s[s * 3 + 0], cy = pos_s[s * 3 + 1], cz = pos_s[s * 3 + 2];
    const float* posb = pos + (size_t)b * N_ * 3;
    int m = 0;
    for (int base = 0; base < N_; base += 64) {
        int p = base + lane;
        float dx = __fsub_rn(posb[3 * p + 0], cx);
        float dy = __fsub_rn(posb[3 * p + 1], cy);
        float dz = __fsub_rn(posb[3 * p + 2], cz);
        float d2 = __fadd_rn(__fadd_rn(__fmul_rn(dx, dx), __fmul_rn(dy, dy)), __fmul_rn(dz, dz));
        bool in = (d2 <= R2_);
        unsigned long long msk = __ballot(in);
        int before = __popcll(msk & ((1ull << lane) - 1ull));
        int slot = m + before;
        if (in && slot < CAP_)
            ck[w][slot] = ((unsigned long long)__float_as_uint(d2) << 32) | (unsigned)p;
        m += __popcll(msk);
    }
    if (m > CAP_) m = CAP_;
    __asm__ volatile("s_waitcnt lgkmcnt(0)" ::: "memory");
    int kcnt = m < K_ ? m : K_;
    unsigned chosen = 0;  // bit r: slot (lane + 64*r) consumed
    for (int k = 0; k < kcnt; ++k) {
        unsigned long long localk = ~0ull; int bslot = -1;
        for (int r = 0; r * 64 + lane < m; ++r) {
            if (chosen & (1u << r)) continue;
            int q = r * 64 + lane;
            unsigned long long key = ck[w][q];
            if (key < localk) { localk = key; bslot = q; }
        }
        unsigned long long bk = localk;
#pragma unroll
        for (int off = 32; off; off >>= 1) {
            unsigned long long o = __shfl_xor(bk, off);
            if (o < bk) bk = o;
        }
        if (localk == bk && bslot >= 0) chosen |= 1u << (bslot >> 6);
        if (lane == 0) nbr[s * K_ + k] = (int)(bk & 0xFFFFFFFFull);
    }
    if (lane == 0) {
        for (int k = kcnt; k < K_; ++k) nbr[s * K_ + k] = -1;
        cntv[s] = (float)kcnt;
    }
}

// ---------------- message MLP v3: 128 thr, S_MSG samples/block -------------
// Register prefetch across the barrier; feat/sdiff double-buffered; all
// global stores deferred to the end; pos-message reduced algebraically:
// aggr_pos_c = (sum_t W2[t,c]*g_c[t] + b2_c*sum_kk diff_c) / cnt,
// g_c[t] = sum_kk diff_c(masked)*e[kk][t]   (in-register, 3 fma per kk).
__global__ __launch_bounds__(128) void msg_kernel(
    const float* __restrict__ x, const float* __restrict__ pos,
    const float* __restrict__ W1, const float* __restrict__ b1,
    const float* __restrict__ W2, const float* __restrict__ b2,
    const float* __restrict__ pos_s, const int* __restrict__ nbr,
    const float* __restrict__ cntv, float* __restrict__ aggr_x,
    float* __restrict__ out_pos)
{
    __shared__ float feat[2][K_][68];    // 17.0 KB
    __shared__ float sdiff[2][K_][4];    // diff(masked) xyz + valid
    __shared__ float gsl[2][4];          // per-wave partial h sums
    const int t = threadIdx.x;
    const int wv = t >> 6;
    const int lane = t & 63;
    const int s0 = blockIdx.x * S_MSG;
    const int k = t >> 2, part = t & 3;

    float w1c[65];
#pragma unroll
    for (int j = 0; j < 65; ++j) w1c[j] = W1[j * H_ + t];
    const float bt = b1[t];
    const float w2c0 = W2[t * 3 + 0], w2c1 = W2[t * 3 + 1], w2c2 = W2[t * 3 + 2];

    // prefetch state (registers)
    float4 xf[4];
    float pdx = 0.f, pdy = 0.f, pdz = 0.f, pdist = 0.f, pvalid = 0.f;

    // ---- prefetch sample s0 ----
    {
        const int s = s0;
        const int bb = s >> 10;
        const int n = nbr[s * K_ + k];
        if (n >= 0) {
            const float4* xr = (const float4*)(x + ((size_t)bb * N_ + n) * D_);
#pragma unroll
            for (int q = 0; q < 4; ++q) xf[q] = xr[part * 4 + q];
            if (part == 0) {
                const float* pj = pos + ((size_t)bb * N_ + n) * 3;
                float dx = __fsub_rn(pj[0], pos_s[s * 3 + 0]);
                float dy = __fsub_rn(pj[1], pos_s[s * 3 + 1]);
                float dz = __fsub_rn(pj[2], pos_s[s * 3 + 2]);
                float d2 = __fadd_rn(__fadd_rn(__fmul_rn(dx, dx), __fmul_rn(dy, dy)), __fmul_rn(dz, dz));
                pdx = dx; pdy = dy; pdz = dz;
                pdist = d2 > 0.f ? sqrtf(d2) : 0.f;
                pvalid = 1.f;
            }
        } else {
            float4 z = make_float4(0.f, 0.f, 0.f, 0.f);
#pragma unroll
            for (int q = 0; q < 4; ++q) xf[q] = z;
            pdx = pdy = pdz = pdist = 0.f; pvalid = 0.f;
        }
    }

    float ags[S_MSG];
    float opos[S_MSG];

    for (int i = 0; i < S_MSG; ++i) {
        const int s = s0 + i;
        const int buf = i & 1;
        // stage prefetched regs into LDS
        {
            float4* fr = (float4*)&feat[buf][k][0];
#pragma unroll
            for (int q = 0; q < 4; ++q) fr[part * 4 + q] = xf[q];
            if (part == 0) {
                feat[buf][k][64] = pdist;
                sdiff[buf][k][0] = pdx; sdiff[buf][k][1] = pdy;
                sdiff[buf][k][2] = pdz; sdiff[buf][k][3] = pvalid;
            }
        }
        __syncthreads();   // barrier A
        // prefetch next sample (register loads overlap the compute below)
        if (i + 1 < S_MSG) {
            const int sn = s + 1;
            const int bb = sn >> 10;
            const int n = nbr[sn * K_ + k];
            if (n >= 0) {
                const float4* xr = (const float4*)(x + ((size_t)bb * N_ + n) * D_);
#pragma unroll
                for (int q = 0; q < 4; ++q) xf[q] = xr[part * 4 + q];
                if (part == 0) {
                    const float* pj = pos + ((size_t)bb * N_ + n) * 3;
                    float dx = __fsub_rn(pj[0], pos_s[sn * 3 + 0]);
                    float dy = __fsub_rn(pj[1], pos_s[sn * 3 + 1]);
                    float dz = __fsub_rn(pj[2], pos_s[sn * 3 + 2]);
                    float d2 = __fadd_rn(__fadd_rn(__fmul_rn(dx, dx), __fmul_rn(dy, dy)), __fmul_rn(dz, dz));
                    pdx = dx; pdy = dy; pdz = dz;
                    pdist = d2 > 0.f ? sqrtf(d2) : 0.f;
                    pvalid = 1.f;
                }
            } else {
                float4 z = make_float4(0.f, 0.f, 0.f, 0.f);
#pragma unroll
                for (int q = 0; q < 4; ++q) xf[q] = z;
                pdx = pdy = pdz = pdist = 0.f; pvalid = 0.f;
            }
        }
        // ---- compute: emb = relu(feat @ W1 + b1) column t ----
        float acc[K_];
#pragma unroll
        for (int kk = 0; kk < K_; ++kk) acc[kk] = 0.f;
#pragma unroll
        for (int j4 = 0; j4 < 16; ++j4) {
#pragma unroll
            for (int kk = 0; kk < K_; ++kk) {
                float4 f = *(const float4*)&feat[buf][kk][j4 * 4];
                float a = acc[kk];
                a = fmaf(f.x, w1c[j4 * 4 + 0], a);
                a = fmaf(f.y, w1c[j4 * 4 + 1], a);
                a = fmaf(f.z, w1c[j4 * 4 + 2], a);
                a = fmaf(f.w, w1c[j4 * 4 + 3], a);
                acc[kk] = a;
            }
        }
        float ag = 0.f, g0 = 0.f, g1 = 0.f, g2 = 0.f;
#pragma unroll
        for (int kk = 0; kk < K_; ++kk) {
            float4 sv = *(const float4*)&sdiff[buf][kk][0];
            float e = fmaf(feat[buf][kk][64], w1c[64], acc[kk]) + bt;
            e = e > 0.f ? e : 0.f;
            ag = fmaf(sv.w, e, ag);
            g0 = fmaf(sv.x, e, g0);
            g1 = fmaf(sv.y, e, g1);
            g2 = fmaf(sv.z, e, g2);
        }
        ags[i] = ag;
        float h0 = g0 * w2c0, h1 = g1 * w2c1, h2 = g2 * w2c2;
#pragma unroll
        for (int off = 32; off; off >>= 1) {
            h0 += __shfl_xor(h0, off);
            h1 += __shfl_xor(h1, off);
            h2 += __shfl_xor(h2, off);
        }
        if (lane == 0) { gsl[wv][0] = h0; gsl[wv][1] = h1; gsl[wv][2] = h2; }
        __syncthreads();   // barrier B
        if (t < 3) {
            float g = gsl[0][t] + gsl[1][t];
            float sd = 0.f;
            for (int kk = 0; kk < K_; ++kk) sd += sdiff[buf][kk][t];
            float cnt = cntv[s]; if (cnt < 1.f) cnt = 1.f;
            opos[i] = pos_s[s * 3 + t] + (g + b2[t] * sd) / cnt;
        }
    }
#pragma unroll
    for (int i = 0; i < S_MSG; ++i)
        aggr_x[(size_t)(s0 + i) * H_ + t] = ags[i];
    if (t < 3) {
#pragma unroll
        for (int i = 0; i < S_MSG; ++i)
            out_pos[(s0 + i) * 3 + t] = opos[i];
    }
}

// ---------------- update GEMM: relu([x_d, aggr_x] @ W3 + b3) ----------------
__global__ __launch_bounds__(128) void out_kernel(
    const float* __restrict__ x, const float* __restrict__ W3,
    const float* __restrict__ b3, const int* __restrict__ idx_i,
    const float* __restrict__ aggr_x, float* __restrict__ out_x)
{
    __shared__ float rows[32][208];
    const int t = threadIdx.x;
    const int s0 = blockIdx.x * 32;
    const int sl = t >> 2, part = t & 3;
    const int s = s0 + sl;
    const int b = s >> 10;
    const int id = idx_i[s];
    {
        const float4* xr = (const float4*)(x + ((size_t)b * N_ + id) * D_);
        float4* rr = (float4*)&rows[sl][0];
#pragma unroll
        for (int q = 0; q < 4; ++q) rr[part * 4 + q] = xr[part * 4 + q];
        const float4* ar = (const float4*)(aggr_x + (size_t)s * H_);
        float4* rr2 = (float4*)&rows[sl][64];
#pragma unroll
        for (int q = 0; q < 8; ++q) rr2[part * 8 + q] = ar[part * 8 + q];
    }
    __syncthreads();
    float acc[32];
#pragma unroll
    for (int i = 0; i < 32; ++i) acc[i] = 0.f;
    for (int j4 = 0; j4 < 48; ++j4) {
        float w0 = W3[(j4 * 4 + 0) * H_ + t];
        float w1 = W3[(j4 * 4 + 1) * H_ + t];
        float w2 = W3[(j4 * 4 + 2) * H_ + t];
        float w3 = W3[(j4 * 4 + 3) * H_ + t];
#pragma unroll
        for (int i = 0; i < 32; ++i) {
            const float4 f = *(const float4*)&rows[i][j4 * 4];
            float a = acc[i];
            a = fmaf(f.x, w0, a); a = fmaf(f.y, w1, a);
            a = fmaf(f.z, w2, a); a = fmaf(f.w, w3, a);
            acc[i] = a;
        }
    }
    const float bb = b3[t];
#pragma unroll
    for (int i = 0; i < 32; ++i) {
        float v = acc[i] + bb;
        v = v > 0.f ? v : 0.f;
        out_x[(size_t)(s0 + i) * H_ + t] = v;
    }
}

extern "C" void kernel_launch(void* const* d_in, const int* in_sizes, int n_in,
                              void* d_out, int out_size, void* d_ws, size_t ws_size,
                              hipStream_t stream) {
    const float* x   = (const float*)d_in[0];
    const float* pos = (const float*)d_in[1];
    const float* W1  = (const float*)d_in[2];
    const float* b1  = (const float*)d_in[3];
    const float* W2  = (const float*)d_in[4];
    const float* b2  = (const float*)d_in[5];
    const float* W3  = (const float*)d_in[6];
    const float* b3  = (const float*)d_in[7];

    float* out_x   = (float*)d_out;                       // [16,1024,128]
    float* out_pos = (float*)d_out + 2097152;             // [16,1024,3]
    float* idx_f   = (float*)d_out + 2146304;             // [16,1024] as float

    char* ws = (char*)d_ws;
    int*   idx_i  = (int*)ws;                  // 16384 ints
    float* pos_s  = (float*)(ws + 65536);      // 49152 floats
    int*   nbr    = (int*)(ws + 262144);       // 524288 ints
    float* cntv   = (float*)(ws + 2359296);    // 16384 floats
    float* aggr_x = (float*)(ws + 2424832);    // 2097152 floats

    fps_kernel<<<B_, 256, 0, stream>>>(pos, idx_i, idx_f, pos_s);
    nbr_kernel<<<(B_ * NS_) / 4, 256, 0, stream>>>(pos, pos_s, nbr, cntv);
    msg_kernel<<<(B_ * NS_) / S_MSG, 128, 0, stream>>>(x, pos, W1, b1, W2, b2,
                                                       pos_s, nbr, cntv, aggr_x, out_pos);
    out_kernel<<<(B_ * NS_) / 32, 128, 0, stream>>>(x, W3, b3, idx_i, aggr_x, out_x);
}

// Round 4
// 1257.303 us; speedup vs baseline: 2.5435x; 1.6178x over previous
//
#include <hip/hip_runtime.h>
#include <math.h>

#define B_ 16
#define N_ 4096
#define D_ 64
#define H_ 128
#define K_ 32
#define NS_ 1024
#define R2_ 0.04f
#define CAP_ 1024

typedef short short8 __attribute__((ext_vector_type(8)));
typedef float f32x4 __attribute__((ext_vector_type(4)));

static __device__ __forceinline__ short f2bf(float f) {
    unsigned u = __float_as_uint(f);
    unsigned r = (u + 0x7FFFu + ((u >> 16) & 1u)) >> 16;   // round-to-nearest-even
    return (short)r;
}

template<int CTRL, int RM>
static __device__ __forceinline__ unsigned dppmov(unsigned v) {
    // old = v -> masked/invalid lanes keep v (identity for max/min)
    return (unsigned)__builtin_amdgcn_update_dpp((int)v, (int)v, CTRL, RM, 0xF, false);
}

// u64 (kh:kl) prefix-max toward lane 63: row_shr 1,2,4,8 then bcast15(0xa), bcast31(0xc)
#define DPP_MAX_STEP(CTRL, RM)                                            \
    {                                                                     \
        unsigned nh = dppmov<CTRL, RM>(kh);                               \
        unsigned nl = dppmov<CTRL, RM>(kl);                               \
        unsigned long long nk = (((unsigned long long)nh) << 32) | nl;    \
        unsigned long long ok = (((unsigned long long)kh) << 32) | kl;    \
        if (nk > ok) { kh = nh; kl = nl; }                                \
    }

#define DPP_MIN_STEP(CTRL, RM)                                            \
    {                                                                     \
        unsigned nh = dppmov<CTRL, RM>(kh);                               \
        unsigned nl = dppmov<CTRL, RM>(kl);                               \
        unsigned long long nk = (((unsigned long long)nh) << 32) | nl;    \
        unsigned long long ok = (((unsigned long long)kh) << 32) | kl;    \
        if (nk < ok) { kh = nh; kl = nl; }                                \
    }

// ---------------- FPS v4: one block (512 thr) per cloud, DPP reductions ----
__global__ __launch_bounds__(512) void fps_kernel(
    const float* __restrict__ pos, int* __restrict__ idx_i,
    float* __restrict__ idx_f, float* __restrict__ pos_s)
{
    __shared__ float4 lpos4[N_];                         // 64 KB
    __shared__ float4 sres[NS_];                         // 16 KB
    __shared__ unsigned long long skey[2][8];
    __shared__ float4 scoord[2][8];
    const int b = blockIdx.x;
    const int t = threadIdx.x;
    const int wv = t >> 6;
    const int lane = t & 63;
    const float* posb = pos + (size_t)b * N_ * 3;
    for (int p = t; p < N_; p += 512)
        lpos4[p] = make_float4(posb[3 * p + 0], posb[3 * p + 1], posb[3 * p + 2], 0.f);
    __syncthreads();

    float px[8], py[8], pz[8], dist[8];
#pragma unroll
    for (int j = 0; j < 8; ++j) {
        float4 v = lpos4[t + 512 * j];
        px[j] = v.x; py[j] = v.y; pz[j] = v.z;
        dist[j] = 1e10f;
    }
    unsigned curidx = 0;
    float4 c0 = lpos4[0];
    float ccx = c0.x, ccy = c0.y, ccz = c0.z;

    for (int ns = 0; ns < NS_; ++ns) {
        if (t == 0)
            sres[ns] = make_float4(ccx, ccy, ccz, __uint_as_float(curidx));
        // ---- update dists + build per-lane packed keys (bit-exact d2 chain) ----
        unsigned long long k[8];
#pragma unroll
        for (int j = 0; j < 8; ++j) {
            float dx = __fsub_rn(px[j], ccx);
            float dy = __fsub_rn(py[j], ccy);
            float dz = __fsub_rn(pz[j], ccz);
            float d2 = __fadd_rn(__fadd_rn(__fmul_rn(dx, dx), __fmul_rn(dy, dy)), __fmul_rn(dz, dz));
            float dn = fminf(dist[j], d2);
            dist[j] = dn;
            k[j] = (((unsigned long long)__float_as_uint(dn)) << 32)
                 | (unsigned long long)(0xFFFFFFFFu - (unsigned)(t + 512 * j));
        }
        // depth-3 tree (max dist, lowest idx on tie via ~idx low bits)
        if (k[1] > k[0]) k[0] = k[1];
        if (k[3] > k[2]) k[2] = k[3];
        if (k[5] > k[4]) k[4] = k[5];
        if (k[7] > k[6]) k[6] = k[7];
        if (k[2] > k[0]) k[0] = k[2];
        if (k[6] > k[4]) k[4] = k[6];
        if (k[4] > k[0]) k[0] = k[4];
        const unsigned long long mykey = k[0];
        unsigned kh = (unsigned)(mykey >> 32), kl = (unsigned)mykey;
        // ---- wave prefix-max to lane 63 via DPP ----
        DPP_MAX_STEP(0x111, 0xF)   // row_shr:1
        DPP_MAX_STEP(0x112, 0xF)   // row_shr:2
        DPP_MAX_STEP(0x114, 0xF)   // row_shr:4
        DPP_MAX_STEP(0x118, 0xF)   // row_shr:8
        DPP_MAX_STEP(0x142, 0xA)   // row_bcast:15 -> rows 1,3
        DPP_MAX_STEP(0x143, 0xC)   // row_bcast:31 -> rows 2,3
        const unsigned mh = (unsigned)__builtin_amdgcn_readlane((int)kh, 63);
        const unsigned ml = (unsigned)__builtin_amdgcn_readlane((int)kl, 63);
        const unsigned long long wkey = (((unsigned long long)mh) << 32) | ml;
        // winner lane: recover its local j from the broadcast idx, select coords
        const unsigned pwin = 0xFFFFFFFFu - ml;
        const unsigned jw = ((pwin - (unsigned)t) >> 9) & 7u;
        float a0x = (jw & 1) ? px[1] : px[0], a1x = (jw & 1) ? px[3] : px[2];
        float a2x = (jw & 1) ? px[5] : px[4], a3x = (jw & 1) ? px[7] : px[6];
        float a0y = (jw & 1) ? py[1] : py[0], a1y = (jw & 1) ? py[3] : py[2];
        float a2y = (jw & 1) ? py[5] : py[4], a3y = (jw & 1) ? py[7] : py[6];
        float a0z = (jw & 1) ? pz[1] : pz[0], a1z = (jw & 1) ? pz[3] : pz[2];
        float a2z = (jw & 1) ? pz[5] : pz[4], a3z = (jw & 1) ? pz[7] : pz[6];
        float b0x = (jw & 2) ? a1x : a0x, b1x = (jw & 2) ? a3x : a2x;
        float b0y = (jw & 2) ? a1y : a0y, b1y = (jw & 2) ? a3y : a2y;
        float b0z = (jw & 2) ? a1z : a0z, b1z = (jw & 2) ? a3z : a2z;
        float wx = (jw & 4) ? b1x : b0x;
        float wy = (jw & 4) ? b1y : b0y;
        float wz = (jw & 4) ? b1z : b0z;
        if (mykey == wkey) {
            skey[ns & 1][wv] = mykey;
            scoord[ns & 1][wv] = make_float4(wx, wy, wz, 0.f);
        }
        __syncthreads();
        // ---- 8-slot tournament via DPP row_shl (all lanes active) ----
        {
            const int sl = lane & 7;
            unsigned long long skv = skey[ns & 1][sl];
            float4 scv = scoord[ns & 1][sl];
            unsigned kh2 = (unsigned)(skv >> 32), kl2 = (unsigned)skv;
            unsigned xu = __float_as_uint(scv.x);
            unsigned yu = __float_as_uint(scv.y);
            unsigned zu = __float_as_uint(scv.z);
#define SLOT_STEP(CTRL)                                                        \
            {                                                                  \
                unsigned nh = dppmov<CTRL, 0xF>(kh2);                          \
                unsigned nl = dppmov<CTRL, 0xF>(kl2);                          \
                unsigned nx = dppmov<CTRL, 0xF>(xu);                           \
                unsigned ny = dppmov<CTRL, 0xF>(yu);                           \
                unsigned nz = dppmov<CTRL, 0xF>(zu);                           \
                unsigned long long nk = (((unsigned long long)nh) << 32) | nl; \
                unsigned long long ok = (((unsigned long long)kh2) << 32) | kl2;\
                if (nk > ok) { kh2 = nh; kl2 = nl; xu = nx; yu = ny; zu = nz; }\
            }
            SLOT_STEP(0x101)   // row_shl:1
            SLOT_STEP(0x102)   // row_shl:2
            SLOT_STEP(0x104)   // row_shl:4
#undef SLOT_STEP
            curidx = 0xFFFFFFFFu - (unsigned)__builtin_amdgcn_readlane((int)kl2, 0);
            ccx = __uint_as_float((unsigned)__builtin_amdgcn_readlane((int)xu, 0));
            ccy = __uint_as_float((unsigned)__builtin_amdgcn_readlane((int)yu, 0));
            ccz = __uint_as_float((unsigned)__builtin_amdgcn_readlane((int)zu, 0));
        }
    }
    __syncthreads();
    for (int i = t; i < NS_; i += 512) {
        float4 r = sres[i];
        unsigned id = __float_as_uint(r.w);
        idx_i[b * NS_ + i] = (int)id;
        idx_f[b * NS_ + i] = (float)id;
        pos_s[(b * NS_ + i) * 3 + 0] = r.x;
        pos_s[(b * NS_ + i) * 3 + 1] = r.y;
        pos_s[(b * NS_ + i) * 3 + 2] = r.z;
    }
}

// ---------------- radius-KNN v3: one wave per sample, DPP min-select -------
__global__ __launch_bounds__(256) void nbr_kernel(
    const float* __restrict__ pos, const float* __restrict__ pos_s,
    int* __restrict__ nbr, float* __restrict__ cntv)
{
    __shared__ unsigned long long ck[4][CAP_];
    const int w = threadIdx.x >> 6;
    const int lane = threadIdx.x & 63;
    const int s = blockIdx.x * 4 + w;
    const int b = s >> 10;
    const float cx = pos_s[s * 3 + 0], cy = pos_s[s * 3 + 1], cz = pos_s[s * 3 + 2];
    const float* posb = pos + (size_t)b * N_ * 3;
    int m = 0;
    for (int base = 0; base < N_; base += 64) {
        int p = base + lane;
        float dx = __fsub_rn(posb[3 * p + 0], cx);
        float dy = __fsub_rn(posb[3 * p + 1], cy);
        float dz = __fsub_rn(posb[3 * p + 2], cz);
        float d2 = __fadd_rn(__fadd_rn(__fmul_rn(dx, dx), __fmul_rn(dy, dy)), __fmul_rn(dz, dz));
        bool in = (d2 <= R2_);
        unsigned long long msk = __ballot(in);
        int before = __popcll(msk & ((1ull << lane) - 1ull));
        int slot = m + before;
        if (in && slot < CAP_)
            ck[w][slot] = ((unsigned long long)__float_as_uint(d2) << 32) | (unsigned)p;
        m += __popcll(msk);
    }
    if (m > CAP_) m = CAP_;
    __asm__ volatile("s_waitcnt lgkmcnt(0)" ::: "memory");
    int kcnt = m < K_ ? m : K_;
    unsigned chosen = 0;
    for (int k = 0; k < kcnt; ++k) {
        unsigned long long localk = ~0ull; int bslot = -1;
        for (int r = 0; r * 64 + lane < m; ++r) {
            if (chosen & (1u << r)) continue;
            int q = r * 64 + lane;
            unsigned long long key = ck[w][q];
            if (key < localk) { localk = key; bslot = q; }
        }
        unsigned kh = (unsigned)(localk >> 32), kl = (unsigned)localk;
        DPP_MIN_STEP(0x111, 0xF)
        DPP_MIN_STEP(0x112, 0xF)
        DPP_MIN_STEP(0x114, 0xF)
        DPP_MIN_STEP(0x118, 0xF)
        DPP_MIN_STEP(0x142, 0xA)
        DPP_MIN_STEP(0x143, 0xC)
        unsigned mh = (unsigned)__builtin_amdgcn_readlane((int)kh, 63);
        unsigned ml = (unsigned)__builtin_amdgcn_readlane((int)kl, 63);
        unsigned long long bk = (((unsigned long long)mh) << 32) | ml;
        if (localk == bk && bslot >= 0) chosen |= 1u << (bslot >> 6);
        if (lane == 0) nbr[s * K_ + k] = (int)(bk & 0xFFFFFFFFull);
    }
    if (lane == 0) {
        for (int k = kcnt; k < K_; ++k) nbr[s * K_ + k] = -1;
        cntv[s] = (float)kcnt;
    }
}

// ---------------- message MLP v4: bf16 MFMA, wave-private, no barriers -----
// D[kk][h] = feat(32x64,bf16) @ W1(64x128,bf16 in regs); dist*W1[64]+b1+relu
// in epilogue; aggregations in-register + cross-quad shfl_xor.
// Per-wave LDS region: feat bf16[32][72] (4608 B) + sdiff f32x4[32] (512 B).
__global__ __launch_bounds__(256) void msg_kernel(
    const float* __restrict__ x, const float* __restrict__ pos,
    const float* __restrict__ W1, const float* __restrict__ b1,
    const float* __restrict__ W2, const float* __restrict__ b2,
    const float* __restrict__ pos_s, const int* __restrict__ nbr,
    const float* __restrict__ cntv, float* __restrict__ aggr_x,
    float* __restrict__ out_pos)
{
    __shared__ __align__(16) char smem[4 * 5120];
    const int t = threadIdx.x;
    const int wv = t >> 6, lane = t & 63;
    const int quad = lane >> 4, cl = lane & 15;
    char* wb = smem + wv * 5120;

    // persistent W1 B-fragments: lane holds B[k=ks*32+quad*8+jj][h=Nt*16+cl]
    short8 bfrag[8][2];
    float b1v[8], w1dv[8], w2v0[8], w2v1[8], w2v2[8];
#pragma unroll
    for (int Nt = 0; Nt < 8; ++Nt) {
        const int h = Nt * 16 + cl;
#pragma unroll
        for (int ks = 0; ks < 2; ++ks) {
            short8 f;
#pragma unroll
            for (int jj = 0; jj < 8; ++jj)
                f[jj] = f2bf(W1[(ks * 32 + quad * 8 + jj) * H_ + h]);
            bfrag[Nt][ks] = f;
        }
        b1v[Nt] = b1[h];
        w1dv[Nt] = W1[64 * H_ + h];
        w2v0[Nt] = W2[h * 3 + 0];
        w2v1[Nt] = W2[h * 3 + 1];
        w2v2[Nt] = W2[h * 3 + 2];
    }
    const float b20 = b2[0], b21 = b2[1], b22 = b2[2];

    const int kkg = lane >> 1, half = lane & 1;
    for (int i = 0; i < 4; ++i) {
        const int s = blockIdx.x * 16 + wv * 4 + i;
        const int b = s >> 10;
        const int n = nbr[s * K_ + kkg];
        // ---- gather neighbor row -> bf16 LDS tile (wave-private) ----
        {
            char* frow = wb + kkg * 144 + half * 64;
            if (n >= 0) {
                const float4* xr = (const float4*)(x + ((size_t)b * N_ + n) * D_) + half * 8;
#pragma unroll
                for (int q = 0; q < 4; ++q) {
                    float4 a = xr[q * 2], c = xr[q * 2 + 1];
                    short8 o;
                    o[0] = f2bf(a.x); o[1] = f2bf(a.y); o[2] = f2bf(a.z); o[3] = f2bf(a.w);
                    o[4] = f2bf(c.x); o[5] = f2bf(c.y); o[6] = f2bf(c.z); o[7] = f2bf(c.w);
                    *(short8*)(frow + q * 16) = o;
                }
            } else {
                short8 z = {0, 0, 0, 0, 0, 0, 0, 0};
#pragma unroll
                for (int q = 0; q < 4; ++q) *(short8*)(frow + q * 16) = z;
            }
            if (half == 0) {
                float dxm = 0.f, dym = 0.f, dzm = 0.f, de = -1.f;
                if (n >= 0) {
                    const float* pj = pos + ((size_t)b * N_ + n) * 3;
                    float dx = pj[0] - pos_s[s * 3 + 0];
                    float dy = pj[1] - pos_s[s * 3 + 1];
                    float dz = pj[2] - pos_s[s * 3 + 2];
                    float d2 = dx * dx + dy * dy + dz * dz;
                    de = d2 > 0.f ? sqrtf(d2) : 0.f;
                    dxm = dx; dym = dy; dzm = dz;
                }
                f32x4 sv = {dxm, dym, dzm, de};
                *(f32x4*)(wb + 4608 + kkg * 16) = sv;
            }
        }
        // same-wave LDS write->read ordering handled by compiler lgkmcnt waits.
        float agp[8] = {0, 0, 0, 0, 0, 0, 0, 0};
        float gp0[8] = {0, 0, 0, 0, 0, 0, 0, 0};
        float gp1[8] = {0, 0, 0, 0, 0, 0, 0, 0};
        float gp2[8] = {0, 0, 0, 0, 0, 0, 0, 0};
#pragma unroll
        for (int Mt = 0; Mt < 2; ++Mt) {
            short8 a0 = *(short8*)(wb + (Mt * 16 + cl) * 144 + quad * 16);
            short8 a1 = *(short8*)(wb + (Mt * 16 + cl) * 144 + 64 + quad * 16);
            f32x4 acc[8];
#pragma unroll
            for (int Nt = 0; Nt < 8; ++Nt) {
                f32x4 z = {0.f, 0.f, 0.f, 0.f};
                z = __builtin_amdgcn_mfma_f32_16x16x32_bf16(a0, bfrag[Nt][0], z, 0, 0, 0);
                z = __builtin_amdgcn_mfma_f32_16x16x32_bf16(a1, bfrag[Nt][1], z, 0, 0, 0);
                acc[Nt] = z;
            }
            f32x4 sd[4];
#pragma unroll
            for (int r = 0; r < 4; ++r)
                sd[r] = *(f32x4*)(wb + 4608 + (Mt * 16 + quad * 4 + r) * 16);
#pragma unroll
            for (int Nt = 0; Nt < 8; ++Nt) {
#pragma unroll
                for (int r = 0; r < 4; ++r) {
                    float dr = sd[r][3];
                    float wgt = dr >= 0.f ? 1.f : 0.f;
                    float dd = dr >= 0.f ? dr : 0.f;
                    float e = fmaf(dd, w1dv[Nt], acc[Nt][r]) + b1v[Nt];
                    e = e > 0.f ? e : 0.f;
                    agp[Nt] = fmaf(wgt, e, agp[Nt]);
                    gp0[Nt] = fmaf(sd[r][0], e, gp0[Nt]);
                    gp1[Nt] = fmaf(sd[r][1], e, gp1[Nt]);
                    gp2[Nt] = fmaf(sd[r][2], e, gp2[Nt]);
                }
            }
        }
        // ---- cross-quad reduce (kk spans quads) + aggr_x store ----
#pragma unroll
        for (int Nt = 0; Nt < 8; ++Nt) {
            float v = agp[Nt]; v += __shfl_xor(v, 16); v += __shfl_xor(v, 32);
            aggr_x[(size_t)s * H_ + Nt * 16 + cl] = v;
            float g0 = gp0[Nt]; g0 += __shfl_xor(g0, 16); g0 += __shfl_xor(g0, 32); gp0[Nt] = g0;
            float g1 = gp1[Nt]; g1 += __shfl_xor(g1, 16); g1 += __shfl_xor(g1, 32); gp1[Nt] = g1;
            float g2 = gp2[Nt]; g2 += __shfl_xor(g2, 16); g2 += __shfl_xor(g2, 32); gp2[Nt] = g2;
        }
        // ---- res_c = sum_h W2[h][c]*g_c[h] ----
        float pr0 = 0.f, pr1 = 0.f, pr2 = 0.f;
#pragma unroll
        for (int Nt = 0; Nt < 8; ++Nt) {
            pr0 = fmaf(w2v0[Nt], gp0[Nt], pr0);
            pr1 = fmaf(w2v1[Nt], gp1[Nt], pr1);
            pr2 = fmaf(w2v2[Nt], gp2[Nt], pr2);
        }
#pragma unroll
        for (int off = 1; off < 16; off <<= 1) {
            pr0 += __shfl_xor(pr0, off);
            pr1 += __shfl_xor(pr1, off);
            pr2 += __shfl_xor(pr2, off);
        }
        // ---- diffsum_c over 32 kk (halves duplicate; reduce within 32) ----
        f32x4 dsv = *(f32x4*)(wb + 4608 + (lane & 31) * 16);
        float q0 = dsv[0], q1 = dsv[1], q2 = dsv[2];
#pragma unroll
        for (int off = 1; off < 32; off <<= 1) {
            q0 += __shfl_xor(q0, off);
            q1 += __shfl_xor(q1, off);
            q2 += __shfl_xor(q2, off);
        }
        float cnt = cntv[s]; if (cnt < 1.f) cnt = 1.f;
        if (lane < 3) {
            float pr = lane == 0 ? pr0 : (lane == 1 ? pr1 : pr2);
            float qq = lane == 0 ? q0 : (lane == 1 ? q1 : q2);
            float bb = lane == 0 ? b20 : (lane == 1 ? b21 : b22);
            out_pos[s * 3 + lane] = pos_s[s * 3 + lane] + (pr + bb * qq) / cnt;
        }
    }
}

// ---------------- update GEMM: relu([x_d, aggr_x] @ W3 + b3) ----------------
__global__ __launch_bounds__(128) void out_kernel(
    const float* __restrict__ x, const float* __restrict__ W3,
    const float* __restrict__ b3, const int* __restrict__ idx_i,
    const float* __restrict__ aggr_x, float* __restrict__ out_x)
{
    __shared__ float rows[32][208];
    const int t = threadIdx.x;
    const int s0 = blockIdx.x * 32;
    const int sl = t >> 2, part = t & 3;
    const int s = s0 + sl;
    const int b = s >> 10;
    const int id = idx_i[s];
    {
        const float4* xr = (const float4*)(x + ((size_t)b * N_ + id) * D_);
        float4* rr = (float4*)&rows[sl][0];
#pragma unroll
        for (int q = 0; q < 4; ++q) rr[part * 4 + q] = xr[part * 4 + q];
        const float4* ar = (const float4*)(aggr_x + (size_t)s * H_);
        float4* rr2 = (float4*)&rows[sl][64];
#pragma unroll
        for (int q = 0; q < 8; ++q) rr2[part * 8 + q] = ar[part * 8 + q];
    }
    __syncthreads();
    float acc[32];
#pragma unroll
    for (int i = 0; i < 32; ++i) acc[i] = 0.f;
    for (int j4 = 0; j4 < 48; ++j4) {
        float w0 = W3[(j4 * 4 + 0) * H_ + t];
        float w1 = W3[(j4 * 4 + 1) * H_ + t];
        float w2 = W3[(j4 * 4 + 2) * H_ + t];
        float w3 = W3[(j4 * 4 + 3) * H_ + t];
#pragma unroll
        for (int i = 0; i < 32; ++i) {
            const float4 f = *(const float4*)&rows[i][j4 * 4];
            float a = acc[i];
            a = fmaf(f.x, w0, a); a = fmaf(f.y, w1, a);
            a = fmaf(f.z, w2, a); a = fmaf(f.w, w3, a);
            acc[i] = a;
        }
    }
    const float bb = b3[t];
#pragma unroll
    for (int i = 0; i < 32; ++i) {
        float v = acc[i] + bb;
        v = v > 0.f ? v : 0.f;
        out_x[(size_t)(s0 + i) * H_ + t] = v;
    }
}

extern "C" void kernel_launch(void* const* d_in, const int* in_sizes, int n_in,
                              void* d_out, int out_size, void* d_ws, size_t ws_size,
                              hipStream_t stream) {
    const float* x   = (const float*)d_in[0];
    const float* pos = (const float*)d_in[1];
    const float* W1  = (const float*)d_in[2];
    const float* b1  = (const float*)d_in[3];
    const float* W2  = (const float*)d_in[4];
    const float* b2  = (const float*)d_in[5];
    const float* W3  = (const float*)d_in[6];
    const float* b3  = (const float*)d_in[7];

    float* out_x   = (float*)d_out;                       // [16,1024,128]
    float* out_pos = (float*)d_out + 2097152;             // [16,1024,3]
    float* idx_f   = (float*)d_out + 2146304;             // [16,1024] as float

    char* ws = (char*)d_ws;
    int*   idx_i  = (int*)ws;                  // 16384 ints
    float* pos_s  = (float*)(ws + 65536);      // 49152 floats
    int*   nbr    = (int*)(ws + 262144);       // 524288 ints
    float* cntv   = (float*)(ws + 2359296);    // 16384 floats
    float* aggr_x = (float*)(ws + 2424832);    // 2097152 floats

    fps_kernel<<<B_, 512, 0, stream>>>(pos, idx_i, idx_f, pos_s);
    nbr_kernel<<<(B_ * NS_) / 4, 256, 0, stream>>>(pos, pos_s, nbr, cntv);
    msg_kernel<<<(B_ * NS_) / 16, 256, 0, stream>>>(x, pos, W1, b1, W2, b2,
                                                    pos_s, nbr, cntv, aggr_x, out_pos);
    out_kernel<<<(B_ * NS_) / 32, 128, 0, stream>>>(x, W3, b3, idx_i, aggr_x, out_x);
}

// Round 5
// 1026.159 us; speedup vs baseline: 3.1164x; 1.2253x over previous
//
#include <hip/hip_runtime.h>
#include <math.h>

#define B_ 16
#define N_ 4096
#define D_ 64
#define H_ 128
#define K_ 32
#define NS_ 1024
#define R2_ 0.04f
#define CAP_ 1024

typedef short short8 __attribute__((ext_vector_type(8)));
typedef float f32x4 __attribute__((ext_vector_type(4)));

static __device__ __forceinline__ short f2bf(float f) {
    unsigned u = __float_as_uint(f);
    unsigned r = (u + 0x7FFFu + ((u >> 16) & 1u)) >> 16;   // round-to-nearest-even
    return (short)r;
}

template<int CTRL, int RM>
static __device__ __forceinline__ unsigned dppmov(unsigned v) {
    // old = v -> masked/invalid lanes keep v (identity for max/min)
    return (unsigned)__builtin_amdgcn_update_dpp((int)v, (int)v, CTRL, RM, 0xF, false);
}

#define DPP_FMAX_STEP(CTRL, RM)                                           \
    {                                                                     \
        float n = __uint_as_float(dppmov<CTRL, RM>(__float_as_uint(wm))); \
        wm = fmaxf(wm, n);                                                \
    }

#define DPP_UMIN_STEP(CTRL, RM)                                           \
    {                                                                     \
        unsigned n = dppmov<CTRL, RM>(cand);                              \
        cand = n < cand ? n : cand;                                       \
    }

#define DPP_MIN_STEP(CTRL, RM)                                            \
    {                                                                     \
        unsigned nh = dppmov<CTRL, RM>(kh);                               \
        unsigned nl = dppmov<CTRL, RM>(kl);                               \
        unsigned long long nk = (((unsigned long long)nh) << 32) | nl;    \
        unsigned long long ok = (((unsigned long long)kh) << 32) | kl;    \
        if (nk < ok) { kh = nh; kl = nl; }                                \
    }

// ---------------- FPS v5: one block (256 thr) per cloud ----------------
// fp32-max DPP phase + u32-idx-min DPP phase (no u64 per-lane machinery),
// coords of the winner fetched via one broadcast ds_read from lpos4[curidx]
// (no coord recovery / carrying). One barrier per iteration.
__global__ __launch_bounds__(256) void fps_kernel(
    const float* __restrict__ pos, int* __restrict__ idx_i,
    float* __restrict__ idx_f, float* __restrict__ pos_s)
{
    __shared__ float4 lpos4[N_];                         // 64 KB
    __shared__ float4 sres[NS_];                         // 16 KB
    __shared__ unsigned long long skey[2][4];
    const int b = blockIdx.x;
    const int t = threadIdx.x;
    const int wv = t >> 6;
    const int lane = t & 63;
    const float* posb = pos + (size_t)b * N_ * 3;
    for (int p = t; p < N_; p += 256)
        lpos4[p] = make_float4(posb[3 * p + 0], posb[3 * p + 1], posb[3 * p + 2], 0.f);
    __syncthreads();

    float px[16], py[16], pz[16], dist[16];
#pragma unroll
    for (int j = 0; j < 16; ++j) {
        float4 v = lpos4[t + 256 * j];
        px[j] = v.x; py[j] = v.y; pz[j] = v.z;
        dist[j] = 1e10f;
    }
    unsigned curidx = 0;
    float4 c0 = lpos4[0];
    float ccx = c0.x, ccy = c0.y, ccz = c0.z;

    for (int ns = 0; ns < NS_; ++ns) {
        if (t == 0)
            sres[ns] = make_float4(ccx, ccy, ccz, __uint_as_float(curidx));
        // ---- update dists + per-lane argmax (bit-exact d2 chain) ----
        float bv = -1.f; int bj = 0;
#pragma unroll
        for (int j = 0; j < 16; ++j) {
            float dx = __fsub_rn(px[j], ccx);
            float dy = __fsub_rn(py[j], ccy);
            float dz = __fsub_rn(pz[j], ccz);
            float d2 = __fadd_rn(__fadd_rn(__fmul_rn(dx, dx), __fmul_rn(dy, dy)), __fmul_rn(dz, dz));
            float dn = fminf(dist[j], d2);
            dist[j] = dn;
            bool g = dn > bv;                 // strict > + ascending j => lowest idx on tie
            bv = g ? dn : bv;
            bj = g ? j : bj;
        }
        // ---- wave fp32 max via DPP (result valid in lane 63) ----
        float wm = bv;
        DPP_FMAX_STEP(0x111, 0xF)   // row_shr:1
        DPP_FMAX_STEP(0x112, 0xF)   // row_shr:2
        DPP_FMAX_STEP(0x114, 0xF)   // row_shr:4
        DPP_FMAX_STEP(0x118, 0xF)   // row_shr:8
        DPP_FMAX_STEP(0x142, 0xA)   // row_bcast:15
        DPP_FMAX_STEP(0x143, 0xC)   // row_bcast:31
        const float wavemax = __uint_as_float(
            (unsigned)__builtin_amdgcn_readlane((int)__float_as_uint(wm), 63));
        // ---- wave u32 idx-min among lanes achieving the max ----
        unsigned cand = (bv == wavemax) ? (unsigned)(t | (bj << 8)) : 0xFFFFFFFFu;
        DPP_UMIN_STEP(0x111, 0xF)
        DPP_UMIN_STEP(0x112, 0xF)
        DPP_UMIN_STEP(0x114, 0xF)
        DPP_UMIN_STEP(0x118, 0xF)
        DPP_UMIN_STEP(0x142, 0xA)
        DPP_UMIN_STEP(0x143, 0xC)
        const unsigned widx = (unsigned)__builtin_amdgcn_readlane((int)cand, 63);
        if (lane == 0)
            skey[ns & 1][wv] = (((unsigned long long)__float_as_uint(wavemax)) << 32)
                             | (unsigned long long)(0xFFFFFFFFu - widx);
        __syncthreads();
        // ---- 4-slot u64-max tournament via DPP row_shl (lane 0 holds winner) ----
        {
            unsigned long long skv = skey[ns & 1][lane & 3];
            unsigned kh2 = (unsigned)(skv >> 32), kl2 = (unsigned)skv;
#define SLOT_STEP(CTRL)                                                        \
            {                                                                  \
                unsigned nh = dppmov<CTRL, 0xF>(kh2);                          \
                unsigned nl = dppmov<CTRL, 0xF>(kl2);                          \
                unsigned long long nk = (((unsigned long long)nh) << 32) | nl; \
                unsigned long long ok = (((unsigned long long)kh2) << 32) | kl2;\
                if (nk > ok) { kh2 = nh; kl2 = nl; }                           \
            }
            SLOT_STEP(0x101)   // row_shl:1
            SLOT_STEP(0x102)   // row_shl:2
#undef SLOT_STEP
            curidx = 0xFFFFFFFFu - (unsigned)__builtin_amdgcn_readlane((int)kl2, 0);
        }
        // winner coords: one broadcast LDS read (same address, all lanes)
        {
            float4 cc = lpos4[curidx];
            ccx = cc.x; ccy = cc.y; ccz = cc.z;
        }
    }
    __syncthreads();
    for (int i = t; i < NS_; i += 256) {
        float4 r = sres[i];
        unsigned id = __float_as_uint(r.w);
        idx_i[b * NS_ + i] = (int)id;
        idx_f[b * NS_ + i] = (float)id;
        pos_s[(b * NS_ + i) * 3 + 0] = r.x;
        pos_s[(b * NS_ + i) * 3 + 1] = r.y;
        pos_s[(b * NS_ + i) * 3 + 2] = r.z;
    }
}

// ---------------- radius-KNN v3: one wave per sample, DPP min-select -------
__global__ __launch_bounds__(256) void nbr_kernel(
    const float* __restrict__ pos, const float* __restrict__ pos_s,
    int* __restrict__ nbr, float* __restrict__ cntv)
{
    __shared__ unsigned long long ck[4][CAP_];
    const int w = threadIdx.x >> 6;
    const int lane = threadIdx.x & 63;
    const int s = blockIdx.x * 4 + w;
    const int b = s >> 10;
    const float cx = pos_s[s * 3 + 0], cy = pos_s[s * 3 + 1], cz = pos_s[s * 3 + 2];
    const float* posb = pos + (size_t)b * N_ * 3;
    int m = 0;
    for (int base = 0; base < N_; base += 64) {
        int p = base + lane;
        float dx = __fsub_rn(posb[3 * p + 0], cx);
        float dy = __fsub_rn(posb[3 * p + 1], cy);
        float dz = __fsub_rn(posb[3 * p + 2], cz);
        float d2 = __fadd_rn(__fadd_rn(__fmul_rn(dx, dx), __fmul_rn(dy, dy)), __fmul_rn(dz, dz));
        bool in = (d2 <= R2_);
        unsigned long long msk = __ballot(in);
        int before = __popcll(msk & ((1ull << lane) - 1ull));
        int slot = m + before;
        if (in && slot < CAP_)
            ck[w][slot] = ((unsigned long long)__float_as_uint(d2) << 32) | (unsigned)p;
        m += __popcll(msk);
    }
    if (m > CAP_) m = CAP_;
    __asm__ volatile("s_waitcnt lgkmcnt(0)" ::: "memory");
    int kcnt = m < K_ ? m : K_;
    unsigned chosen = 0;
    for (int k = 0; k < kcnt; ++k) {
        unsigned long long localk = ~0ull; int bslot = -1;
        for (int r = 0; r * 64 + lane < m; ++r) {
            if (chosen & (1u << r)) continue;
            int q = r * 64 + lane;
            unsigned long long key = ck[w][q];
            if (key < localk) { localk = key; bslot = q; }
        }
        unsigned kh = (unsigned)(localk >> 32), kl = (unsigned)localk;
        DPP_MIN_STEP(0x111, 0xF)
        DPP_MIN_STEP(0x112, 0xF)
        DPP_MIN_STEP(0x114, 0xF)
        DPP_MIN_STEP(0x118, 0xF)
        DPP_MIN_STEP(0x142, 0xA)
        DPP_MIN_STEP(0x143, 0xC)
        unsigned mh = (unsigned)__builtin_amdgcn_readlane((int)kh, 63);
        unsigned ml = (unsigned)__builtin_amdgcn_readlane((int)kl, 63);
        unsigned long long bk = (((unsigned long long)mh) << 32) | ml;
        if (localk == bk && bslot >= 0) chosen |= 1u << (bslot >> 6);
        if (lane == 0) nbr[s * K_ + k] = (int)(bk & 0xFFFFFFFFull);
    }
    if (lane == 0) {
        for (int k = kcnt; k < K_; ++k) nbr[s * K_ + k] = -1;
        cntv[s] = (float)kcnt;
    }
}

// ---------------- message MLP v4: bf16 MFMA, wave-private, no barriers -----
__global__ __launch_bounds__(256) void msg_kernel(
    const float* __restrict__ x, const float* __restrict__ pos,
    const float* __restrict__ W1, const float* __restrict__ b1,
    const float* __restrict__ W2, const float* __restrict__ b2,
    const float* __restrict__ pos_s, const int* __restrict__ nbr,
    const float* __restrict__ cntv, float* __restrict__ aggr_x,
    float* __restrict__ out_pos)
{
    __shared__ __align__(16) char smem[4 * 5120];
    const int t = threadIdx.x;
    const int wv = t >> 6, lane = t & 63;
    const int quad = lane >> 4, cl = lane & 15;
    char* wb = smem + wv * 5120;

    short8 bfrag[8][2];
    float b1v[8], w1dv[8], w2v0[8], w2v1[8], w2v2[8];
#pragma unroll
    for (int Nt = 0; Nt < 8; ++Nt) {
        const int h = Nt * 16 + cl;
#pragma unroll
        for (int ks = 0; ks < 2; ++ks) {
            short8 f;
#pragma unroll
            for (int jj = 0; jj < 8; ++jj)
                f[jj] = f2bf(W1[(ks * 32 + quad * 8 + jj) * H_ + h]);
            bfrag[Nt][ks] = f;
        }
        b1v[Nt] = b1[h];
        w1dv[Nt] = W1[64 * H_ + h];
        w2v0[Nt] = W2[h * 3 + 0];
        w2v1[Nt] = W2[h * 3 + 1];
        w2v2[Nt] = W2[h * 3 + 2];
    }
    const float b20 = b2[0], b21 = b2[1], b22 = b2[2];

    const int kkg = lane >> 1, half = lane & 1;
    for (int i = 0; i < 4; ++i) {
        const int s = blockIdx.x * 16 + wv * 4 + i;
        const int b = s >> 10;
        const int n = nbr[s * K_ + kkg];
        {
            char* frow = wb + kkg * 144 + half * 64;
            if (n >= 0) {
                const float4* xr = (const float4*)(x + ((size_t)b * N_ + n) * D_) + half * 8;
#pragma unroll
                for (int q = 0; q < 4; ++q) {
                    float4 a = xr[q * 2], c = xr[q * 2 + 1];
                    short8 o;
                    o[0] = f2bf(a.x); o[1] = f2bf(a.y); o[2] = f2bf(a.z); o[3] = f2bf(a.w);
                    o[4] = f2bf(c.x); o[5] = f2bf(c.y); o[6] = f2bf(c.z); o[7] = f2bf(c.w);
                    *(short8*)(frow + q * 16) = o;
                }
            } else {
                short8 z = {0, 0, 0, 0, 0, 0, 0, 0};
#pragma unroll
                for (int q = 0; q < 4; ++q) *(short8*)(frow + q * 16) = z;
            }
            if (half == 0) {
                float dxm = 0.f, dym = 0.f, dzm = 0.f, de = -1.f;
                if (n >= 0) {
                    const float* pj = pos + ((size_t)b * N_ + n) * 3;
                    float dx = pj[0] - pos_s[s * 3 + 0];
                    float dy = pj[1] - pos_s[s * 3 + 1];
                    float dz = pj[2] - pos_s[s * 3 + 2];
                    float d2 = dx * dx + dy * dy + dz * dz;
                    de = d2 > 0.f ? sqrtf(d2) : 0.f;
                    dxm = dx; dym = dy; dzm = dz;
                }
                f32x4 sv = {dxm, dym, dzm, de};
                *(f32x4*)(wb + 4608 + kkg * 16) = sv;
            }
        }
        float agp[8] = {0, 0, 0, 0, 0, 0, 0, 0};
        float gp0[8] = {0, 0, 0, 0, 0, 0, 0, 0};
        float gp1[8] = {0, 0, 0, 0, 0, 0, 0, 0};
        float gp2[8] = {0, 0, 0, 0, 0, 0, 0, 0};
#pragma unroll
        for (int Mt = 0; Mt < 2; ++Mt) {
            short8 a0 = *(short8*)(wb + (Mt * 16 + cl) * 144 + quad * 16);
            short8 a1 = *(short8*)(wb + (Mt * 16 + cl) * 144 + 64 + quad * 16);
            f32x4 acc[8];
#pragma unroll
            for (int Nt = 0; Nt < 8; ++Nt) {
                f32x4 z = {0.f, 0.f, 0.f, 0.f};
                z = __builtin_amdgcn_mfma_f32_16x16x32_bf16(a0, bfrag[Nt][0], z, 0, 0, 0);
                z = __builtin_amdgcn_mfma_f32_16x16x32_bf16(a1, bfrag[Nt][1], z, 0, 0, 0);
                acc[Nt] = z;
            }
            f32x4 sd[4];
#pragma unroll
            for (int r = 0; r < 4; ++r)
                sd[r] = *(f32x4*)(wb + 4608 + (Mt * 16 + quad * 4 + r) * 16);
#pragma unroll
            for (int Nt = 0; Nt < 8; ++Nt) {
#pragma unroll
                for (int r = 0; r < 4; ++r) {
                    float dr = sd[r][3];
                    float wgt = dr >= 0.f ? 1.f : 0.f;
                    float dd = dr >= 0.f ? dr : 0.f;
                    float e = fmaf(dd, w1dv[Nt], acc[Nt][r]) + b1v[Nt];
                    e = e > 0.f ? e : 0.f;
                    agp[Nt] = fmaf(wgt, e, agp[Nt]);
                    gp0[Nt] = fmaf(sd[r][0], e, gp0[Nt]);
                    gp1[Nt] = fmaf(sd[r][1], e, gp1[Nt]);
                    gp2[Nt] = fmaf(sd[r][2], e, gp2[Nt]);
                }
            }
        }
#pragma unroll
        for (int Nt = 0; Nt < 8; ++Nt) {
            float v = agp[Nt]; v += __shfl_xor(v, 16); v += __shfl_xor(v, 32);
            aggr_x[(size_t)s * H_ + Nt * 16 + cl] = v;
            float g0 = gp0[Nt]; g0 += __shfl_xor(g0, 16); g0 += __shfl_xor(g0, 32); gp0[Nt] = g0;
            float g1 = gp1[Nt]; g1 += __shfl_xor(g1, 16); g1 += __shfl_xor(g1, 32); gp1[Nt] = g1;
            float g2 = gp2[Nt]; g2 += __shfl_xor(g2, 16); g2 += __shfl_xor(g2, 32); gp2[Nt] = g2;
        }
        float pr0 = 0.f, pr1 = 0.f, pr2 = 0.f;
#pragma unroll
        for (int Nt = 0; Nt < 8; ++Nt) {
            pr0 = fmaf(w2v0[Nt], gp0[Nt], pr0);
            pr1 = fmaf(w2v1[Nt], gp1[Nt], pr1);
            pr2 = fmaf(w2v2[Nt], gp2[Nt], pr2);
        }
#pragma unroll
        for (int off = 1; off < 16; off <<= 1) {
            pr0 += __shfl_xor(pr0, off);
            pr1 += __shfl_xor(pr1, off);
            pr2 += __shfl_xor(pr2, off);
        }
        f32x4 dsv = *(f32x4*)(wb + 4608 + (lane & 31) * 16);
        float q0 = dsv[0], q1 = dsv[1], q2 = dsv[2];
#pragma unroll
        for (int off = 1; off < 32; off <<= 1) {
            q0 += __shfl_xor(q0, off);
            q1 += __shfl_xor(q1, off);
            q2 += __shfl_xor(q2, off);
        }
        float cnt = cntv[s]; if (cnt < 1.f) cnt = 1.f;
        if (lane < 3) {
            float pr = lane == 0 ? pr0 : (lane == 1 ? pr1 : pr2);
            float qq = lane == 0 ? q0 : (lane == 1 ? q1 : q2);
            float bb = lane == 0 ? b20 : (lane == 1 ? b21 : b22);
            out_pos[s * 3 + lane] = pos_s[s * 3 + lane] + (pr + bb * qq) / cnt;
        }
    }
}

// ---------------- update GEMM: relu([x_d, aggr_x] @ W3 + b3) ----------------
__global__ __launch_bounds__(128) void out_kernel(
    const float* __restrict__ x, const float* __restrict__ W3,
    const float* __restrict__ b3, const int* __restrict__ idx_i,
    const float* __restrict__ aggr_x, float* __restrict__ out_x)
{
    __shared__ float rows[32][208];
    const int t = threadIdx.x;
    const int s0 = blockIdx.x * 32;
    const int sl = t >> 2, part = t & 3;
    const int s = s0 + sl;
    const int b = s >> 10;
    const int id = idx_i[s];
    {
        const float4* xr = (const float4*)(x + ((size_t)b * N_ + id) * D_);
        float4* rr = (float4*)&rows[sl][0];
#pragma unroll
        for (int q = 0; q < 4; ++q) rr[part * 4 + q] = xr[part * 4 + q];
        const float4* ar = (const float4*)(aggr_x + (size_t)s * H_);
        float4* rr2 = (float4*)&rows[sl][64];
#pragma unroll
        for (int q = 0; q < 8; ++q) rr2[part * 8 + q] = ar[part * 8 + q];
    }
    __syncthreads();
    float acc[32];
#pragma unroll
    for (int i = 0; i < 32; ++i) acc[i] = 0.f;
    for (int j4 = 0; j4 < 48; ++j4) {
        float w0 = W3[(j4 * 4 + 0) * H_ + t];
        float w1 = W3[(j4 * 4 + 1) * H_ + t];
        float w2 = W3[(j4 * 4 + 2) * H_ + t];
        float w3 = W3[(j4 * 4 + 3) * H_ + t];
#pragma unroll
        for (int i = 0; i < 32; ++i) {
            const float4 f = *(const float4*)&rows[i][j4 * 4];
            float a = acc[i];
            a = fmaf(f.x, w0, a); a = fmaf(f.y, w1, a);
            a = fmaf(f.z, w2, a); a = fmaf(f.w, w3, a);
            acc[i] = a;
        }
    }
    const float bb = b3[t];
#pragma unroll
    for (int i = 0; i < 32; ++i) {
        float v = acc[i] + bb;
        v = v > 0.f ? v : 0.f;
        out_x[(size_t)(s0 + i) * H_ + t] = v;
    }
}

extern "C" void kernel_launch(void* const* d_in, const int* in_sizes, int n_in,
                              void* d_out, int out_size, void* d_ws, size_t ws_size,
                              hipStream_t stream) {
    const float* x   = (const float*)d_in[0];
    const float* pos = (const float*)d_in[1];
    const float* W1  = (const float*)d_in[2];
    const float* b1  = (const float*)d_in[3];
    const float* W2  = (const float*)d_in[4];
    const float* b2  = (const float*)d_in[5];
    const float* W3  = (const float*)d_in[6];
    const float* b3  = (const float*)d_in[7];

    float* out_x   = (float*)d_out;                       // [16,1024,128]
    float* out_pos = (float*)d_out + 2097152;             // [16,1024,3]
    float* idx_f   = (float*)d_out + 2146304;             // [16,1024] as float

    char* ws = (char*)d_ws;
    int*   idx_i  = (int*)ws;                  // 16384 ints
    float* pos_s  = (float*)(ws + 65536);      // 49152 floats
    int*   nbr    = (int*)(ws + 262144);       // 524288 ints
    float* cntv   = (float*)(ws + 2359296);    // 16384 floats
    float* aggr_x = (float*)(ws + 2424832);    // 2097152 floats

    fps_kernel<<<B_, 256, 0, stream>>>(pos, idx_i, idx_f, pos_s);
    nbr_kernel<<<(B_ * NS_) / 4, 256, 0, stream>>>(pos, pos_s, nbr, cntv);
    msg_kernel<<<(B_ * NS_) / 16, 256, 0, stream>>>(x, pos, W1, b1, W2, b2,
                                                    pos_s, nbr, cntv, aggr_x, out_pos);
    out_kernel<<<(B_ * NS_) / 32, 128, 0, stream>>>(x, W3, b3, idx_i, aggr_x, out_x);
}

// Round 6
// 987.195 us; speedup vs baseline: 3.2394x; 1.0395x over previous
//
#include <hip/hip_runtime.h>
#include <math.h>

#define B_ 16
#define N_ 4096
#define D_ 64
#define H_ 128
#define K_ 32
#define NS_ 1024
#define R2_ 0.04f
#define CAP_ 1024

typedef short short8 __attribute__((ext_vector_type(8)));
typedef float f32x4 __attribute__((ext_vector_type(4)));
typedef unsigned short ushort_t;

static __device__ __forceinline__ short f2bf(float f) {
    unsigned u = __float_as_uint(f);
    unsigned r = (u + 0x7FFFu + ((u >> 16) & 1u)) >> 16;   // round-to-nearest-even
    return (short)r;
}

template<int CTRL, int RM>
static __device__ __forceinline__ unsigned dppmov(unsigned v) {
    // old = v -> masked/invalid lanes keep v (identity for max/min)
    return (unsigned)__builtin_amdgcn_update_dpp((int)v, (int)v, CTRL, RM, 0xF, false);
}

#define DPP_FMAX_STEP(CTRL, RM)                                           \
    {                                                                     \
        float n = __uint_as_float(dppmov<CTRL, RM>(__float_as_uint(wm))); \
        wm = fmaxf(wm, n);                                                \
    }

#define DPP_UMIN_STEP(CTRL, RM)                                           \
    {                                                                     \
        unsigned n = dppmov<CTRL, RM>(cand);                              \
        cand = n < cand ? n : cand;                                       \
    }

#define DPP_MIN_STEP(CTRL, RM)                                            \
    {                                                                     \
        unsigned nh = dppmov<CTRL, RM>(kh);                               \
        unsigned nl = dppmov<CTRL, RM>(kl);                               \
        unsigned long long nk = (((unsigned long long)nh) << 32) | nl;    \
        unsigned long long ok = (((unsigned long long)kh) << 32) | kl;    \
        if (nk < ok) { kh = nh; kl = nl; }                                \
    }

// ---------------- x -> bf16 pre-convert (RNE, identical to f2bf) ----------
__global__ __launch_bounds__(256) void cvt_kernel(
    const float* __restrict__ x, ushort_t* __restrict__ xb)
{
    const size_t i = ((size_t)blockIdx.x * 256 + threadIdx.x) * 8;
    float4 a = *(const float4*)(x + i);
    float4 c = *(const float4*)(x + i + 4);
    short8 o;
    o[0] = f2bf(a.x); o[1] = f2bf(a.y); o[2] = f2bf(a.z); o[3] = f2bf(a.w);
    o[4] = f2bf(c.x); o[5] = f2bf(c.y); o[6] = f2bf(c.z); o[7] = f2bf(c.w);
    *(short8*)(xb + i) = o;
}

// ---------------- FPS v6: one block (256 thr) per cloud ----------------
// launch_bounds(256,1): allow high VGPR so px/py/pz/dist stay register-resident.
// fp32-max DPP + ballot fast-path idx (exact umin fallback on rare ties).
__global__ __launch_bounds__(256, 1) void fps_kernel(
    const float* __restrict__ pos, int* __restrict__ idx_i,
    float* __restrict__ idx_f, float* __restrict__ pos_s)
{
    __shared__ float4 lpos4[N_];                         // 64 KB
    __shared__ float4 sres[NS_];                         // 16 KB
    __shared__ unsigned long long skey[2][4];
    const int b = blockIdx.x;
    const int t = threadIdx.x;
    const int wv = t >> 6;
    const int lane = t & 63;
    const float* posb = pos + (size_t)b * N_ * 3;
    for (int p = t; p < N_; p += 256)
        lpos4[p] = make_float4(posb[3 * p + 0], posb[3 * p + 1], posb[3 * p + 2], 0.f);
    __syncthreads();

    float px[16], py[16], pz[16], dist[16];
#pragma unroll
    for (int j = 0; j < 16; ++j) {
        float4 v = lpos4[t + 256 * j];
        px[j] = v.x; py[j] = v.y; pz[j] = v.z;
        dist[j] = 1e10f;
    }
    unsigned curidx = 0;
    float4 c0 = lpos4[0];
    float ccx = c0.x, ccy = c0.y, ccz = c0.z;

    for (int ns = 0; ns < NS_; ++ns) {
        if (t == 0)
            sres[ns] = make_float4(ccx, ccy, ccz, __uint_as_float(curidx));
        // ---- update dists + per-lane argmax (bit-exact d2 chain) ----
        float bv = -1.f; int bj = 0;
#pragma unroll
        for (int j = 0; j < 16; ++j) {
            float dx = __fsub_rn(px[j], ccx);
            float dy = __fsub_rn(py[j], ccy);
            float dz = __fsub_rn(pz[j], ccz);
            float d2 = __fadd_rn(__fadd_rn(__fmul_rn(dx, dx), __fmul_rn(dy, dy)), __fmul_rn(dz, dz));
            float dn = fminf(dist[j], d2);
            dist[j] = dn;
            bool g = dn > bv;                 // strict > + ascending j => lowest idx on tie
            bv = g ? dn : bv;
            bj = g ? j : bj;
        }
        // ---- wave fp32 max via DPP (result valid in lane 63) ----
        float wm = bv;
        DPP_FMAX_STEP(0x111, 0xF)   // row_shr:1
        DPP_FMAX_STEP(0x112, 0xF)   // row_shr:2
        DPP_FMAX_STEP(0x114, 0xF)   // row_shr:4
        DPP_FMAX_STEP(0x118, 0xF)   // row_shr:8
        DPP_FMAX_STEP(0x142, 0xA)   // row_bcast:15
        DPP_FMAX_STEP(0x143, 0xC)   // row_bcast:31
        const float wavemax = __uint_as_float(
            (unsigned)__builtin_amdgcn_readlane((int)__float_as_uint(wm), 63));
        // ---- min global idx among max-achieving lanes ----
        const unsigned pidx = (unsigned)t + ((unsigned)bj << 8);   // == global point idx
        const unsigned long long mask = __ballot(bv == wavemax);
        unsigned widx;
        if (__popcll(mask) == 1) {             // unique winner (common case)
            const int wl = __ffsll((long long)mask) - 1;
            widx = (unsigned)__builtin_amdgcn_readlane((int)pidx, wl);
        } else {                                // exact tie fallback
            unsigned cand = (bv == wavemax) ? pidx : 0xFFFFFFFFu;
            DPP_UMIN_STEP(0x111, 0xF)
            DPP_UMIN_STEP(0x112, 0xF)
            DPP_UMIN_STEP(0x114, 0xF)
            DPP_UMIN_STEP(0x118, 0xF)
            DPP_UMIN_STEP(0x142, 0xA)
            DPP_UMIN_STEP(0x143, 0xC)
            widx = (unsigned)__builtin_amdgcn_readlane((int)cand, 63);
        }
        if (lane == 0)
            skey[ns & 1][wv] = (((unsigned long long)__float_as_uint(wavemax)) << 32)
                             | (unsigned long long)(0xFFFFFFFFu - widx);
        __syncthreads();
        // ---- 4-slot u64-max tournament via DPP row_shl (lane 0 holds winner) ----
        {
            unsigned long long skv = skey[ns & 1][lane & 3];
            unsigned kh2 = (unsigned)(skv >> 32), kl2 = (unsigned)skv;
#define SLOT_STEP(CTRL)                                                        \
            {                                                                  \
                unsigned nh = dppmov<CTRL, 0xF>(kh2);                          \
                unsigned nl = dppmov<CTRL, 0xF>(kl2);                          \
                unsigned long long nk = (((unsigned long long)nh) << 32) | nl; \
                unsigned long long ok = (((unsigned long long)kh2) << 32) | kl2;\
                if (nk > ok) { kh2 = nh; kl2 = nl; }                           \
            }
            SLOT_STEP(0x101)   // row_shl:1
            SLOT_STEP(0x102)   // row_shl:2
#undef SLOT_STEP
            curidx = 0xFFFFFFFFu - (unsigned)__builtin_amdgcn_readlane((int)kl2, 0);
        }
        // winner coords: one broadcast LDS read (same address, all lanes)
        {
            float4 cc = lpos4[curidx];
            ccx = cc.x; ccy = cc.y; ccz = cc.z;
        }
    }
    __syncthreads();
    for (int i = t; i < NS_; i += 256) {
        float4 r = sres[i];
        unsigned id = __float_as_uint(r.w);
        idx_i[b * NS_ + i] = (int)id;
        idx_f[b * NS_ + i] = (float)id;
        pos_s[(b * NS_ + i) * 3 + 0] = r.x;
        pos_s[(b * NS_ + i) * 3 + 1] = r.y;
        pos_s[(b * NS_ + i) * 3 + 2] = r.z;
    }
}

// ---------------- radius-KNN v4: register-resident selection ----------------
__global__ __launch_bounds__(256) void nbr_kernel(
    const float* __restrict__ pos, const float* __restrict__ pos_s,
    int* __restrict__ nbr, float* __restrict__ cntv)
{
    __shared__ unsigned long long ck[4][CAP_];
    const int w = threadIdx.x >> 6;
    const int lane = threadIdx.x & 63;
    const int s = blockIdx.x * 4 + w;
    const int b = s >> 10;
    const float cx = pos_s[s * 3 + 0], cy = pos_s[s * 3 + 1], cz = pos_s[s * 3 + 2];
    const float* posb = pos + (size_t)b * N_ * 3;
    int m = 0;
    for (int base = 0; base < N_; base += 64) {
        int p = base + lane;
        float dx = __fsub_rn(posb[3 * p + 0], cx);
        float dy = __fsub_rn(posb[3 * p + 1], cy);
        float dz = __fsub_rn(posb[3 * p + 2], cz);
        float d2 = __fadd_rn(__fadd_rn(__fmul_rn(dx, dx), __fmul_rn(dy, dy)), __fmul_rn(dz, dz));
        bool in = (d2 <= R2_);
        unsigned long long msk = __ballot(in);
        int before = __popcll(msk & ((1ull << lane) - 1ull));
        int slot = m + before;
        if (in && slot < CAP_)
            ck[w][slot] = ((unsigned long long)__float_as_uint(d2) << 32) | (unsigned)p;
        m += __popcll(msk);
    }
    if (m > CAP_) m = CAP_;
    __asm__ volatile("s_waitcnt lgkmcnt(0)" ::: "memory");
    int kcnt = m < K_ ? m : K_;
    if (m <= 384) {
        // load candidate keys once into registers; selection is pure VALU/DPP
        unsigned long long kr[6];
#pragma unroll
        for (int r = 0; r < 6; ++r) {
            int q = r * 64 + lane;
            unsigned long long v = ck[w][q & (CAP_ - 1)];
            kr[r] = (q < m) ? v : ~0ull;
        }
        unsigned chosen = 0;
        for (int k = 0; k < kcnt; ++k) {
            unsigned long long localk = ~0ull; int br = -1;
#pragma unroll
            for (int r = 0; r < 6; ++r) {
                bool ok = (!((chosen >> r) & 1u)) && (kr[r] < localk);
                localk = ok ? kr[r] : localk;
                br = ok ? r : br;
            }
            unsigned kh = (unsigned)(localk >> 32), kl = (unsigned)localk;
            DPP_MIN_STEP(0x111, 0xF)
            DPP_MIN_STEP(0x112, 0xF)
            DPP_MIN_STEP(0x114, 0xF)
            DPP_MIN_STEP(0x118, 0xF)
            DPP_MIN_STEP(0x142, 0xA)
            DPP_MIN_STEP(0x143, 0xC)
            unsigned mh = (unsigned)__builtin_amdgcn_readlane((int)kh, 63);
            unsigned ml = (unsigned)__builtin_amdgcn_readlane((int)kl, 63);
            unsigned long long bk = (((unsigned long long)mh) << 32) | ml;
            if (localk == bk && br >= 0) chosen |= 1u << br;
            if (lane == 0) nbr[s * K_ + k] = (int)(bk & 0xFFFFFFFFull);
        }
    } else {
        // exact fallback (rare): LDS-scan selection
        unsigned chosen = 0;
        for (int k = 0; k < kcnt; ++k) {
            unsigned long long localk = ~0ull; int bslot = -1;
            for (int r = 0; r * 64 + lane < m; ++r) {
                if (chosen & (1u << r)) continue;
                int q = r * 64 + lane;
                unsigned long long key = ck[w][q];
                if (key < localk) { localk = key; bslot = q; }
            }
            unsigned kh = (unsigned)(localk >> 32), kl = (unsigned)localk;
            DPP_MIN_STEP(0x111, 0xF)
            DPP_MIN_STEP(0x112, 0xF)
            DPP_MIN_STEP(0x114, 0xF)
            DPP_MIN_STEP(0x118, 0xF)
            DPP_MIN_STEP(0x142, 0xA)
            DPP_MIN_STEP(0x143, 0xC)
            unsigned mh = (unsigned)__builtin_amdgcn_readlane((int)kh, 63);
            unsigned ml = (unsigned)__builtin_amdgcn_readlane((int)kl, 63);
            unsigned long long bk = (((unsigned long long)mh) << 32) | ml;
            if (localk == bk && bslot >= 0) chosen |= 1u << (bslot >> 6);
            if (lane == 0) nbr[s * K_ + k] = (int)(bk & 0xFFFFFFFFull);
        }
    }
    if (lane == 0) {
        for (int k = kcnt; k < K_; ++k) nbr[s * K_ + k] = -1;
        cntv[s] = (float)kcnt;
    }
}

// ---------------- message MLP v5: bf16 MFMA, pre-converted x ----------------
__global__ __launch_bounds__(256) void msg_kernel(
    const ushort_t* __restrict__ xb, const float* __restrict__ pos,
    const float* __restrict__ W1, const float* __restrict__ b1,
    const float* __restrict__ W2, const float* __restrict__ b2,
    const float* __restrict__ pos_s, const int* __restrict__ nbr,
    const float* __restrict__ cntv, float* __restrict__ aggr_x,
    float* __restrict__ out_pos)
{
    __shared__ __align__(16) char smem[4 * 5120];
    const int t = threadIdx.x;
    const int wv = t >> 6, lane = t & 63;
    const int quad = lane >> 4, cl = lane & 15;
    char* wb = smem + wv * 5120;

    short8 bfrag[8][2];
    float b1v[8], w1dv[8], w2v0[8], w2v1[8], w2v2[8];
#pragma unroll
    for (int Nt = 0; Nt < 8; ++Nt) {
        const int h = Nt * 16 + cl;
#pragma unroll
        for (int ks = 0; ks < 2; ++ks) {
            short8 f;
#pragma unroll
            for (int jj = 0; jj < 8; ++jj)
                f[jj] = f2bf(W1[(ks * 32 + quad * 8 + jj) * H_ + h]);
            bfrag[Nt][ks] = f;
        }
        b1v[Nt] = b1[h];
        w1dv[Nt] = W1[64 * H_ + h];
        w2v0[Nt] = W2[h * 3 + 0];
        w2v1[Nt] = W2[h * 3 + 1];
        w2v2[Nt] = W2[h * 3 + 2];
    }
    const float b20 = b2[0], b21 = b2[1], b22 = b2[2];

    const int kkg = lane >> 1, half = lane & 1;
    for (int i = 0; i < 4; ++i) {
        const int s = blockIdx.x * 16 + wv * 4 + i;
        const int b = s >> 10;
        const int n = nbr[s * K_ + kkg];
        {
            char* frow = wb + kkg * 144 + half * 64;
            if (n >= 0) {
                const short8* xr = (const short8*)(xb + ((size_t)b * N_ + n) * D_) + half * 4;
#pragma unroll
                for (int q = 0; q < 4; ++q) *(short8*)(frow + q * 16) = xr[q];
            } else {
                short8 z = {0, 0, 0, 0, 0, 0, 0, 0};
#pragma unroll
                for (int q = 0; q < 4; ++q) *(short8*)(frow + q * 16) = z;
            }
            if (half == 0) {
                float dxm = 0.f, dym = 0.f, dzm = 0.f, de = -1.f;
                if (n >= 0) {
                    const float* pj = pos + ((size_t)b * N_ + n) * 3;
                    float dx = pj[0] - pos_s[s * 3 + 0];
                    float dy = pj[1] - pos_s[s * 3 + 1];
                    float dz = pj[2] - pos_s[s * 3 + 2];
                    float d2 = dx * dx + dy * dy + dz * dz;
                    de = d2 > 0.f ? sqrtf(d2) : 0.f;
                    dxm = dx; dym = dy; dzm = dz;
                }
                f32x4 sv = {dxm, dym, dzm, de};
                *(f32x4*)(wb + 4608 + kkg * 16) = sv;
            }
        }
        float agp[8] = {0, 0, 0, 0, 0, 0, 0, 0};
        float gp0[8] = {0, 0, 0, 0, 0, 0, 0, 0};
        float gp1[8] = {0, 0, 0, 0, 0, 0, 0, 0};
        float gp2[8] = {0, 0, 0, 0, 0, 0, 0, 0};
#pragma unroll
        for (int Mt = 0; Mt < 2; ++Mt) {
            short8 a0 = *(short8*)(wb + (Mt * 16 + cl) * 144 + quad * 16);
            short8 a1 = *(short8*)(wb + (Mt * 16 + cl) * 144 + 64 + quad * 16);
            f32x4 acc[8];
#pragma unroll
            for (int Nt = 0; Nt < 8; ++Nt) {
                f32x4 z = {0.f, 0.f, 0.f, 0.f};
                z = __builtin_amdgcn_mfma_f32_16x16x32_bf16(a0, bfrag[Nt][0], z, 0, 0, 0);
                z = __builtin_amdgcn_mfma_f32_16x16x32_bf16(a1, bfrag[Nt][1], z, 0, 0, 0);
                acc[Nt] = z;
            }
            f32x4 sd[4];
#pragma unroll
            for (int r = 0; r < 4; ++r)
                sd[r] = *(f32x4*)(wb + 4608 + (Mt * 16 + quad * 4 + r) * 16);
#pragma unroll
            for (int Nt = 0; Nt < 8; ++Nt) {
#pragma unroll
                for (int r = 0; r < 4; ++r) {
                    float dr = sd[r][3];
                    float wgt = dr >= 0.f ? 1.f : 0.f;
                    float dd = dr >= 0.f ? dr : 0.f;
                    float e = fmaf(dd, w1dv[Nt], acc[Nt][r]) + b1v[Nt];
                    e = e > 0.f ? e : 0.f;
                    agp[Nt] = fmaf(wgt, e, agp[Nt]);
                    gp0[Nt] = fmaf(sd[r][0], e, gp0[Nt]);
                    gp1[Nt] = fmaf(sd[r][1], e, gp1[Nt]);
                    gp2[Nt] = fmaf(sd[r][2], e, gp2[Nt]);
                }
            }
        }
#pragma unroll
        for (int Nt = 0; Nt < 8; ++Nt) {
            float v = agp[Nt]; v += __shfl_xor(v, 16); v += __shfl_xor(v, 32);
            aggr_x[(size_t)s * H_ + Nt * 16 + cl] = v;
            float g0 = gp0[Nt]; g0 += __shfl_xor(g0, 16); g0 += __shfl_xor(g0, 32); gp0[Nt] = g0;
            float g1 = gp1[Nt]; g1 += __shfl_xor(g1, 16); g1 += __shfl_xor(g1, 32); gp1[Nt] = g1;
            float g2 = gp2[Nt]; g2 += __shfl_xor(g2, 16); g2 += __shfl_xor(g2, 32); gp2[Nt] = g2;
        }
        float pr0 = 0.f, pr1 = 0.f, pr2 = 0.f;
#pragma unroll
        for (int Nt = 0; Nt < 8; ++Nt) {
            pr0 = fmaf(w2v0[Nt], gp0[Nt], pr0);
            pr1 = fmaf(w2v1[Nt], gp1[Nt], pr1);
            pr2 = fmaf(w2v2[Nt], gp2[Nt], pr2);
        }
#pragma unroll
        for (int off = 1; off < 16; off <<= 1) {
            pr0 += __shfl_xor(pr0, off);
            pr1 += __shfl_xor(pr1, off);
            pr2 += __shfl_xor(pr2, off);
        }
        f32x4 dsv = *(f32x4*)(wb + 4608 + (lane & 31) * 16);
        float q0 = dsv[0], q1 = dsv[1], q2 = dsv[2];
#pragma unroll
        for (int off = 1; off < 32; off <<= 1) {
            q0 += __shfl_xor(q0, off);
            q1 += __shfl_xor(q1, off);
            q2 += __shfl_xor(q2, off);
        }
        float cnt = cntv[s]; if (cnt < 1.f) cnt = 1.f;
        if (lane < 3) {
            float pr = lane == 0 ? pr0 : (lane == 1 ? pr1 : pr2);
            float qq = lane == 0 ? q0 : (lane == 1 ? q1 : q2);
            float bb = lane == 0 ? b20 : (lane == 1 ? b21 : b22);
            out_pos[s * 3 + lane] = pos_s[s * 3 + lane] + (pr + bb * qq) / cnt;
        }
    }
}

// ---------------- update GEMM: relu([x_d, aggr_x] @ W3 + b3) ----------------
__global__ __launch_bounds__(128) void out_kernel(
    const float* __restrict__ x, const float* __restrict__ W3,
    const float* __restrict__ b3, const int* __restrict__ idx_i,
    const float* __restrict__ aggr_x, float* __restrict__ out_x)
{
    __shared__ float rows[32][208];
    const int t = threadIdx.x;
    const int s0 = blockIdx.x * 32;
    const int sl = t >> 2, part = t & 3;
    const int s = s0 + sl;
    const int b = s >> 10;
    const int id = idx_i[s];
    {
        const float4* xr = (const float4*)(x + ((size_t)b * N_ + id) * D_);
        float4* rr = (float4*)&rows[sl][0];
#pragma unroll
        for (int q = 0; q < 4; ++q) rr[part * 4 + q] = xr[part * 4 + q];
        const float4* ar = (const float4*)(aggr_x + (size_t)s * H_);
        float4* rr2 = (float4*)&rows[sl][64];
#pragma unroll
        for (int q = 0; q < 8; ++q) rr2[part * 8 + q] = ar[part * 8 + q];
    }
    __syncthreads();
    float acc[32];
#pragma unroll
    for (int i = 0; i < 32; ++i) acc[i] = 0.f;
    for (int j4 = 0; j4 < 48; ++j4) {
        float w0 = W3[(j4 * 4 + 0) * H_ + t];
        float w1 = W3[(j4 * 4 + 1) * H_ + t];
        float w2 = W3[(j4 * 4 + 2) * H_ + t];
        float w3 = W3[(j4 * 4 + 3) * H_ + t];
#pragma unroll
        for (int i = 0; i < 32; ++i) {
            const float4 f = *(const float4*)&rows[i][j4 * 4];
            float a = acc[i];
            a = fmaf(f.x, w0, a); a = fmaf(f.y, w1, a);
            a = fmaf(f.z, w2, a); a = fmaf(f.w, w3, a);
            acc[i] = a;
        }
    }
    const float bb = b3[t];
#pragma unroll
    for (int i = 0; i < 32; ++i) {
        float v = acc[i] + bb;
        v = v > 0.f ? v : 0.f;
        out_x[(size_t)(s0 + i) * H_ + t] = v;
    }
}

extern "C" void kernel_launch(void* const* d_in, const int* in_sizes, int n_in,
                              void* d_out, int out_size, void* d_ws, size_t ws_size,
                              hipStream_t stream) {
    const float* x   = (const float*)d_in[0];
    const float* pos = (const float*)d_in[1];
    const float* W1  = (const float*)d_in[2];
    const float* b1  = (const float*)d_in[3];
    const float* W2  = (const float*)d_in[4];
    const float* b2  = (const float*)d_in[5];
    const float* W3  = (const float*)d_in[6];
    const float* b3  = (const float*)d_in[7];

    float* out_x   = (float*)d_out;                       // [16,1024,128]
    float* out_pos = (float*)d_out + 2097152;             // [16,1024,3]
    float* idx_f   = (float*)d_out + 2146304;             // [16,1024] as float

    char* ws = (char*)d_ws;
    int*      idx_i  = (int*)ws;                   // 16384 ints
    float*    pos_s  = (float*)(ws + 65536);       // 49152 floats
    int*      nbr    = (int*)(ws + 262144);        // 524288 ints
    float*    cntv   = (float*)(ws + 2359296);     // 16384 floats
    float*    aggr_x = (float*)(ws + 2424832);     // 2097152 floats
    ushort_t* x_bf16 = (ushort_t*)(ws + 10813440); // 16777216 ushorts (ends ~19.2MB)

    cvt_kernel<<<(B_ * N_ * D_) / (256 * 8), 256, 0, stream>>>(x, x_bf16);
    fps_kernel<<<B_, 256, 0, stream>>>(pos, idx_i, idx_f, pos_s);
    nbr_kernel<<<(B_ * NS_) / 4, 256, 0, stream>>>(pos, pos_s, nbr, cntv);
    msg_kernel<<<(B_ * NS_) / 16, 256, 0, stream>>>(x_bf16, pos, W1, b1, W2, b2,
                                                    pos_s, nbr, cntv, aggr_x, out_pos);
    out_kernel<<<(B_ * NS_) / 32, 128, 0, stream>>>(x, W3, b3, idx_i, aggr_x, out_x);
}